// Round 11
// baseline (313.730 us; speedup 1.0000x reference)
//
#include <hip/hip_runtime.h>

// B=256, F=16, FO=32, J=22, H=8, IN=256, OUT=512, HID=64, HS=32
// Degenerate-einsum analysis:
//   attn_s = qsum (x) ksum  (outer product of channel sums)
//   x_s    = diag(softmax(attn_s)) * (sum_u v_s')
//   x_t    = sum_f v_t  (softmax sums to 1; q_t/k_t/conv_t/mask_t unused)
// Round 11: qsum/ksum -> barrier-free streaming VALU kernel (qk_stream):
// wave = 8 rows x 8 outputs, f32-exact, no MFMA/staging/barriers in loop.
// vproj stays as R10's verified branch (own kernel). final2 unchanged.

#define NEGV (-1000000000.0f)

typedef __attribute__((ext_vector_type(8))) short short8;
typedef __attribute__((ext_vector_type(4))) float f32x4;

__device__ inline ushort f2bf(float f) {
  union { float f; unsigned u; } a;
  a.f = f;
  unsigned u = a.u;
  return (ushort)((u + 0x7FFFu + ((u >> 16) & 1u)) >> 16);  // RNE
}

// stage 44 rows x 256 f32 -> bf16 into lA with granule swizzle gp = gl ^ (row&7)
#define PUTG(g, pa, pb)                                                        \
  {                                                                            \
    int row_ = (g) >> 5, gl_ = (g) & 31;                                       \
    int gp_ = gl_ ^ (row_ & 7);                                                \
    short8 u_;                                                                 \
    u_[0] = (short)f2bf(pa.x); u_[1] = (short)f2bf(pa.y);                      \
    u_[2] = (short)f2bf(pa.z); u_[3] = (short)f2bf(pa.w);                      \
    u_[4] = (short)f2bf(pb.x); u_[5] = (short)f2bf(pb.y);                      \
    u_[6] = (short)f2bf(pb.z); u_[7] = (short)f2bf(pb.w);                      \
    *reinterpret_cast<short8*>(&lA[row_ * 256 + gp_ * 8]) = u_;                \
  }

#define STAGE44(SRCPTR)                                                        \
  {                                                                            \
    const float* vsrc_ = (SRCPTR);                                             \
    int g0 = tid, g1 = tid + 512, g2 = tid + 1024;                             \
    float4 a0 = *reinterpret_cast<const float4*>(vsrc_ + g0 * 8);              \
    float4 b0 = *reinterpret_cast<const float4*>(vsrc_ + g0 * 8 + 4);          \
    float4 a1 = *reinterpret_cast<const float4*>(vsrc_ + g1 * 8);              \
    float4 b1 = *reinterpret_cast<const float4*>(vsrc_ + g1 * 8 + 4);          \
    float4 a2 = {0, 0, 0, 0}, b2 = {0, 0, 0, 0};                               \
    if (g2 < 1408) {                                                           \
      a2 = *reinterpret_cast<const float4*>(vsrc_ + g2 * 8);                   \
      b2 = *reinterpret_cast<const float4*>(vsrc_ + g2 * 8 + 4);               \
    }                                                                          \
    PUTG(g0, a0, b0);                                                          \
    PUTG(g1, a1, b1);                                                          \
    if (g2 < 1408) PUTG(g2, a2, b2);                                           \
    if (tid < 128) {                                                           \
      int g = 1408 + tid;                                                      \
      int row_ = g >> 5, gp_ = (g & 31) ^ (row_ & 7);                          \
      short8 z = {0, 0, 0, 0, 0, 0, 0, 0};                                     \
      *reinterpret_cast<short8*>(&lA[row_ * 256 + gp_ * 8]) = z;               \
    }                                                                          \
  }

// ---- prep_all2: wvt (bx 0..255) + summed-weight tables (bx 256..263) ----
__global__ __launch_bounds__(512) void prep_all2_kernel(const float* __restrict__ Wq_w,
                                                        const float* __restrict__ Wq_b,
                                                        const float* __restrict__ Wk_w,
                                                        const float* __restrict__ Wk_b,
                                                        const float* __restrict__ Wv_w,
                                                        ushort* __restrict__ wvtf,
                                                        float* __restrict__ sqwT,
                                                        float* __restrict__ skwT,
                                                        float* __restrict__ sqb,
                                                        float* __restrict__ skb) {
  int bx = blockIdx.x, tid = threadIdx.x;
  if (bx < 256) {
    int idx = bx * 512 + tid;  // 0..131071
    int e = idx & 7;
    int lane = (idx >> 3) & 63;
    int ks = (idx >> 9) & 7;
    int nt = idx >> 12;
    int r0 = lane & 15, kb = lane >> 4;
    int k = ks * 32 + kb * 8 + e;
    int ch = nt * 16 + r0;
    wvtf[idx] = f2bf(Wv_w[k * 512 + ch]);
  } else {
    int sub = bx - 256;           // 0..7
    int which = sub >> 2;         // 0=q, 1=k
    int idx = (sub & 3) * 512 + tid;  // 0..2047 = m*256 + i
    int m = idx >> 8, i = idx & 255;
    const float* W = which ? Wk_w : Wq_w;
    const float4* p = reinterpret_cast<const float4*>(W + (size_t)i * 512 + m * 64);
    float s = 0.f;
    #pragma unroll
    for (int c4 = 0; c4 < 8; ++c4) {
      float4 x = p[c4];
      s += x.x + x.y + x.z + x.w;
    }
    (which ? skwT : sqwT)[idx] = s;
    if (sub == 0 && tid < 8) {
      float b = 0.f;
      for (int c = 0; c < 32; ++c) b += Wq_b[tid * 64 + c];
      sqb[tid] = b;
    }
    if (sub == 4 && tid < 8) {
      float b = 0.f;
      for (int c = 0; c < 32; ++c) b += Wk_b[tid * 64 + c];
      skb[tid] = b;
    }
  }
}

// ---- qk_stream: barrier-free channel-sum streams for q and k ----
// wave = 8 rows x 8 m-outputs. lane (r,m): acc = sum_i row[i]*wT[m][i].
// q rows: 180224 (22528 groups of 8); k rows: 90112 (11264 groups).
__global__ __launch_bounds__(256) void qk_stream_kernel(const float* __restrict__ q,
                                                        const float* __restrict__ k,
                                                        const float* __restrict__ sqwT,
                                                        const float* __restrict__ skwT,
                                                        const float* __restrict__ sqb,
                                                        const float* __restrict__ skb,
                                                        float* __restrict__ qsum,
                                                        float* __restrict__ ksumraw) {
  __shared__ float wq[8][260];
  __shared__ float wk[8][260];
  int tid = threadIdx.x;
  for (int idx = tid; idx < 2048; idx += 256) {
    wq[idx >> 8][idx & 255] = sqwT[idx];
    wk[idx >> 8][idx & 255] = skwT[idx];
  }
  __syncthreads();
  int lane = tid & 63;
  int r = lane >> 3, m = lane & 7;
  float bq = sqb[m], bk = skb[m];
  int wid = blockIdx.x * 4 + (tid >> 6);  // 0..8191
  const int NQ = 22528, NTOT = 33792;
  for (int g = wid; g < NTOT; g += 8192) {
    bool isK = g >= NQ;
    int gg = isK ? g - NQ : g;
    int R = gg * 8 + r;
    const float* src = (isK ? k : q) + (size_t)R * 256;
    const float(*wT)[260] = isK ? wk : wq;
    float acc = 0.f;
    #pragma unroll 4
    for (int i0 = 0; i0 < 256; i0 += 8) {
      float4 qa = *reinterpret_cast<const float4*>(src + i0);
      float4 qb2 = *reinterpret_cast<const float4*>(src + i0 + 4);
      float4 wa = *reinterpret_cast<const float4*>(&wT[m][i0]);
      float4 wb = *reinterpret_cast<const float4*>(&wT[m][i0 + 4]);
      acc += qa.x * wa.x + qa.y * wa.y + qa.z * wa.z + qa.w * wa.w +
             qb2.x * wb.x + qb2.y * wb.y + qb2.z * wb.z + qb2.w * wb.w;
    }
    if (!isK) {
      int b = R / 704, rem = R % 704;
      int fo2 = rem / 22, j2 = rem % 22;
      int lf = (fo2 & 3) * 11264 + j2 * 512 + m * 64;
      int t = lf / 1408;
      int s = (lf % 1408) >> 6;
      int h = fo2 >> 2;
      qsum[(((size_t)b * 8 + h) * 32 + t) * 22 + s] = acc + bq;
    } else {
      int b = R / 352, rem = R % 352;
      int f2 = rem / 22, j2 = rem % 22;
      int lf = (f2 & 1) * 11264 + j2 * 512 + m * 64;
      int floc = lf / 1408;
      int jj = (lf % 1408) >> 6;
      int h = f2 >> 1;
      ksumraw[(((size_t)b * 8 + h) * 16 + floc) * 22 + jj] = acc + bk;
    }
  }
}

// ---- vproj: MFMA + 4-phase dump/gather (R10-verified body, own kernel) ----
__global__ __launch_bounds__(512, 2) void vproj_kernel(const float* __restrict__ v,
                                                       const ushort* __restrict__ wvtf,
                                                       const float* __restrict__ Wv_b,
                                                       float* __restrict__ vs_inner,
                                                       float* __restrict__ vtsum) {
  int bh = blockIdx.x;  // 0..2047
  __shared__ float sbuf[6656];  // lA (24.6KB); reused as dump
  ushort* lA = reinterpret_cast<ushort*>(sbuf);
  float* dump = sbuf;
  int tid = threadIdx.x, lane = tid & 63, w = tid >> 6;
  int r0 = lane & 15, kb = lane >> 4;

  STAGE44(v + (size_t)bh * 11264);
  __syncthreads();

  int nt0 = w * 4;
  f32x4 acc[3][4];
  #pragma unroll
  for (int m = 0; m < 3; ++m)
    #pragma unroll
    for (int n = 0; n < 4; ++n) acc[m][n] = (f32x4){0.f, 0.f, 0.f, 0.f};

  #pragma unroll
  for (int ks = 0; ks < 8; ++ks) {
    int go = ((ks * 4 + kb) ^ (r0 & 7)) * 8;
    short8 a0 = *reinterpret_cast<const short8*>(&lA[(r0) * 256 + go]);
    short8 a1 = *reinterpret_cast<const short8*>(&lA[(16 + r0) * 256 + go]);
    short8 a2 = *reinterpret_cast<const short8*>(&lA[(32 + r0) * 256 + go]);
    #pragma unroll
    for (int n = 0; n < 4; ++n) {
      short8 bf = *reinterpret_cast<const short8*>(
          wvtf + ((size_t)((nt0 + n) * 8 + ks) * 64 + lane) * 8);
      acc[0][n] = __builtin_amdgcn_mfma_f32_16x16x32_bf16(bf, a0, acc[0][n], 0, 0, 0);
      acc[1][n] = __builtin_amdgcn_mfma_f32_16x16x32_bf16(bf, a1, acc[1][n], 0, 0, 0);
      acc[2][n] = __builtin_amdgcn_mfma_f32_16x16x32_bf16(bf, a2, acc[2][n], 0, 0, 0);
    }
  }
  __syncthreads();  // lA reads done; sbuf becomes dump

  #pragma unroll
  for (int n = 0; n < 4; ++n) {
    float4 bq = *reinterpret_cast<const float4*>(Wv_b + w * 64 + n * 16 + kb * 4);
    int dbase = tid * 13;
    #pragma unroll
    for (int m = 0; m < 3; ++m) {
      dump[dbase + m * 4 + 0] = acc[m][n][0] + bq.x;
      dump[dbase + m * 4 + 1] = acc[m][n][1] + bq.y;
      dump[dbase + m * 4 + 2] = acc[m][n][2] + bq.z;
      dump[dbase + m * 4 + 3] = acc[m][n][3] + bq.w;
    }
    __syncthreads();
    if (n < 2) {
      if (tid < 256) {
        int f = tid >> 4, rest = tid & 15;
        int kb2 = rest >> 2, reg = rest & 3;
        float s = 0.f;
        #pragma unroll
        for (int u = 0; u < 22; ++u) {
          int fj = f * 22 + u;
          int f2 = (fj >= 176) ? 1 : 0;
          int rem = fj - f2 * 176;
          int j = rem >> 3, ww = rem & 7;
          int vrow = f2 * 22 + j;
          int m = vrow >> 4, rr = vrow & 15;
          s += dump[(ww * 64 + kb2 * 16 + rr) * 13 + m * 4 + reg];
        }
        vs_inner[(size_t)bh * 512 + f * 32 + n * 16 + kb2 * 4 + reg] = s;
      }
    } else {
      if (tid < 352) {
        int jj = tid >> 4, rest = tid & 15;
        int kb2 = rest >> 2, reg = rest & 3;
        float s = 0.f;
        #pragma unroll
        for (int f = 0; f < 16; ++f) {
          int fj = f * 22 + jj;
          int f2 = (fj >= 176) ? 1 : 0;
          int rem = fj - f2 * 176;
          int j = rem >> 3, ww = rem & 7;
          int vrow = f2 * 22 + j;
          int m = vrow >> 4, rr = vrow & 15;
          s += dump[(ww * 64 + kb2 * 16 + rr) * 13 + m * 4 + reg];
        }
        vtsum[(size_t)bh * 704 + jj * 32 + (n - 2) * 16 + kb2 * 4 + reg] = s;
      }
    }
    __syncthreads();
  }
}

// ---- final2: conv_s (k & v) + diag softmax + output, 2 t/block (R10) ----
__global__ __launch_bounds__(512, 2) void final2_kernel(const float* __restrict__ qsum,
                                                        const float* __restrict__ ksumraw,
                                                        const float* __restrict__ vs_inner,
                                                        const float* __restrict__ vtsum,
                                                        const int* __restrict__ mask_s,
                                                        const float* __restrict__ csw,
                                                        const float* __restrict__ csb,
                                                        float* __restrict__ out) {
  int blk = blockIdx.x;  // b*16 + tp
  int tp = blk & 15, b = blk >> 4;
  int t0 = tp * 2;
  __shared__ float vtl[8][704];
  __shared__ float vsi[8][16][32];
  __shared__ float kraw[8][16][22];
  __shared__ float ql2[2][8][22];
  __shared__ float klrow[2][8][22];
  __shared__ float vss[2][8][32];
  __shared__ float dg2[2][8][22];
  __shared__ float lcw[2][18];
  __shared__ int msk[484];
  int tid = threadIdx.x;
  size_t bb = (size_t)b;

  {
    const float4* p = reinterpret_cast<const float4*>(vtsum + bb * 5632);
    float4* dst = reinterpret_cast<float4*>(&vtl[0][0]);
    for (int i = tid; i < 1408; i += 512) dst[i] = p[i];
  }
  {
    const float4* p = reinterpret_cast<const float4*>(vs_inner + bb * 4096);
    float4* dst = reinterpret_cast<float4*>(&vsi[0][0][0]);
    for (int i = tid; i < 1024; i += 512) dst[i] = p[i];
  }
  {
    const float4* p = reinterpret_cast<const float4*>(ksumraw + bb * 2816);
    float4* dst = reinterpret_cast<float4*>(&kraw[0][0][0]);
    for (int i = tid; i < 704; i += 512) dst[i] = p[i];
  }
  if (tid < 352) {
    int tt = tid / 176, r = tid % 176;
    int h = r / 22, s = r % 22;
    ql2[tt][h][s] = qsum[((bb * 8 + h) * 32 + t0 + tt) * 22 + s];
  }
  if (tid < 484) msk[tid] = mask_s[tid];
  if (tid < 32) {
    int tt = tid >> 4, f = tid & 15;
    lcw[tt][f] = csw[(t0 + tt) * 16 + f];
  }
  if (tid >= 32 && tid < 34) lcw[tid - 32][16] = csb[t0 + (tid - 32)];
  __syncthreads();

  if (tid < 352) {
    int tt = tid / 176, r = tid % 176;
    int h = r / 22, j = r % 22;
    float a = 32.0f * lcw[tt][16];
    #pragma unroll
    for (int f = 0; f < 16; ++f) a += lcw[tt][f] * kraw[h][f][j];
    klrow[tt][h][j] = a;
  }
  {
    int tt = tid >> 8, r = tid & 255;
    int h = r >> 5, d = r & 31;
    float a = 22.0f * lcw[tt][16];
    #pragma unroll
    for (int f = 0; f < 16; ++f) a += lcw[tt][f] * vsi[h][f][d];
    vss[tt][h][d] = a;
  }
  __syncthreads();

  if (tid < 352) {
    int tt = tid / 176, r = tid % 176;
    int h = r / 22, s = r % 22;
    float qv = ql2[tt][h][s];
    float mx = -3.0e38f;
    #pragma unroll
    for (int u = 0; u < 22; ++u) {
      float av = msk[s * 22 + u] ? qv * klrow[tt][h][u] : NEGV;
      mx = fmaxf(mx, av);
    }
    float den = 0.f;
    #pragma unroll
    for (int u = 0; u < 22; ++u) {
      float av = msk[s * 22 + u] ? qv * klrow[tt][h][u] : NEGV;
      den += expf(av - mx);
    }
    float as = msk[s * 22 + s] ? qv * klrow[tt][h][s] : NEGV;
    dg2[tt][h][s] = expf(as - mx) / den;
  }
  __syncthreads();

  #pragma unroll
  for (int tt = 0; tt < 2; ++tt) {
    float4* ob4 = reinterpret_cast<float4*>(out + (size_t)(b * 32 + t0 + tt) * 11264);
    #pragma unroll
    for (int it = 0; it < 6; ++it) {
      int i4 = tid + it * 512;  // 0..2815
      if (i4 < 2816) {
        int s = i4 >> 7;
        int ch4 = i4 & 127;
        int h = ch4 >> 4;
        int d0 = (ch4 & 15) * 4;
        float4 val;
        if (d0 < 32) {
          float g = dg2[tt][h][s];
          const float* vp = &vss[tt][h][d0];
          val.x = g * vp[0]; val.y = g * vp[1]; val.z = g * vp[2]; val.w = g * vp[3];
        } else {
          const float* tpn = &vtl[h][s * 32 + d0 - 32];
          val.x = tpn[0]; val.y = tpn[1]; val.z = tpn[2]; val.w = tpn[3];
        }
        ob4[i4] = val;
      }
    }
  }
}

extern "C" void kernel_launch(void* const* d_in, const int* in_sizes, int n_in,
                              void* d_out, int out_size, void* d_ws, size_t ws_size,
                              hipStream_t stream) {
  const float* q = (const float*)d_in[0];
  const float* k = (const float*)d_in[1];
  const float* v = (const float*)d_in[2];
  const int* mask_s = (const int*)d_in[3];
  const float* Wq_w = (const float*)d_in[5];
  const float* Wq_b = (const float*)d_in[6];
  const float* Wk_w = (const float*)d_in[7];
  const float* Wk_b = (const float*)d_in[8];
  const float* Wv_w = (const float*)d_in[9];
  const float* Wv_b = (const float*)d_in[10];
  const float* csw = (const float*)d_in[11];
  const float* csb = (const float*)d_in[12];
  float* out = (float*)d_out;

  float* ws = (float*)d_ws;
  float* sqb = ws;                            // 8
  float* skb = ws + 8;                        // 8 -> 16
  ushort* wvtf = (ushort*)(ws + 16);          // 131072 us -> ends f-idx 65552
  float* sqwT = ws + 65552;                   // 2048 -> 67600
  float* skwT = ws + 67600;                   // 2048 -> 69648
  float* qsum = ws + 69648;                   // 1441792
  float* ksumraw = qsum + 1441792;            // 720896
  float* vs_inner = ksumraw + 720896;         // 1048576
  float* vtsum = vs_inner + 1048576;          // 1441792

  hipLaunchKernelGGL(prep_all2_kernel, dim3(264), dim3(512), 0, stream,
                     Wq_w, Wq_b, Wk_w, Wk_b, Wv_w, wvtf, sqwT, skwT, sqb, skb);
  hipLaunchKernelGGL(qk_stream_kernel, dim3(2048), dim3(256), 0, stream,
                     q, k, sqwT, skwT, sqb, skb, qsum, ksumraw);
  hipLaunchKernelGGL(vproj_kernel, dim3(2048), dim3(512), 0, stream,
                     v, wvtf, Wv_b, vs_inner, vtsum);
  hipLaunchKernelGGL(final2_kernel, dim3(4096), dim3(512), 0, stream,
                     qsum, ksumraw, vs_inner, vtsum, mask_s, csw, csb, out);
}

// Round 12
// 283.217 us; speedup vs baseline: 1.1077x; 1.1077x over previous
//
#include <hip/hip_runtime.h>

// B=256, F=16, FO=32, J=22, H=8, IN=256, OUT=512, HID=64, HS=32
// Degenerate-einsum analysis:
//   attn_s = qsum (x) ksum  (outer product of channel sums)
//   x_s    = diag(softmax(attn_s)) * (sum_u v_s')
//   x_t    = sum_f v_t  (softmax sums to 1; q_t/k_t/conv_t/mask_t unused)
// Round 12: qk_direct — barrier-free, LDS-free q/k channel-sums. Each wave
// owns a 16-row tile (no cross-wave sharing in the verified qsum2 math),
// loads A-frags straight from global, 8 MFMAs vs L1-resident qwf/kwf,
// scatters 4 outputs (R11-verified index math). vproj/final2/prep unchanged.

#define NEGV (-1000000000.0f)

typedef __attribute__((ext_vector_type(8))) short short8;
typedef __attribute__((ext_vector_type(4))) float f32x4;

__device__ inline ushort f2bf(float f) {
  union { float f; unsigned u; } a;
  a.f = f;
  unsigned u = a.u;
  return (ushort)((u + 0x7FFFu + ((u >> 16) & 1u)) >> 16);  // RNE
}

// stage 44 rows x 256 f32 -> bf16 into lA with granule swizzle gp = gl ^ (row&7)
#define PUTG(g, pa, pb)                                                        \
  {                                                                            \
    int row_ = (g) >> 5, gl_ = (g) & 31;                                       \
    int gp_ = gl_ ^ (row_ & 7);                                                \
    short8 u_;                                                                 \
    u_[0] = (short)f2bf(pa.x); u_[1] = (short)f2bf(pa.y);                      \
    u_[2] = (short)f2bf(pa.z); u_[3] = (short)f2bf(pa.w);                      \
    u_[4] = (short)f2bf(pb.x); u_[5] = (short)f2bf(pb.y);                      \
    u_[6] = (short)f2bf(pb.z); u_[7] = (short)f2bf(pb.w);                      \
    *reinterpret_cast<short8*>(&lA[row_ * 256 + gp_ * 8]) = u_;                \
  }

#define STAGE44(SRCPTR)                                                        \
  {                                                                            \
    const float* vsrc_ = (SRCPTR);                                             \
    int g0 = tid, g1 = tid + 512, g2 = tid + 1024;                             \
    float4 a0 = *reinterpret_cast<const float4*>(vsrc_ + g0 * 8);              \
    float4 b0 = *reinterpret_cast<const float4*>(vsrc_ + g0 * 8 + 4);          \
    float4 a1 = *reinterpret_cast<const float4*>(vsrc_ + g1 * 8);              \
    float4 b1 = *reinterpret_cast<const float4*>(vsrc_ + g1 * 8 + 4);          \
    float4 a2 = {0, 0, 0, 0}, b2 = {0, 0, 0, 0};                               \
    if (g2 < 1408) {                                                           \
      a2 = *reinterpret_cast<const float4*>(vsrc_ + g2 * 8);                   \
      b2 = *reinterpret_cast<const float4*>(vsrc_ + g2 * 8 + 4);               \
    }                                                                          \
    PUTG(g0, a0, b0);                                                          \
    PUTG(g1, a1, b1);                                                          \
    if (g2 < 1408) PUTG(g2, a2, b2);                                           \
    if (tid < 128) {                                                           \
      int g = 1408 + tid;                                                      \
      int row_ = g >> 5, gp_ = (g & 31) ^ (row_ & 7);                          \
      short8 z = {0, 0, 0, 0, 0, 0, 0, 0};                                     \
      *reinterpret_cast<short8*>(&lA[row_ * 256 + gp_ * 8]) = z;               \
    }                                                                          \
  }

// ---------------- prep_all: wvt (0..255) + qkwf (256..271) + prepb (272) ----
__global__ __launch_bounds__(512) void prep_all_kernel(const float* __restrict__ Wq_w,
                                                       const float* __restrict__ Wq_b,
                                                       const float* __restrict__ Wk_w,
                                                       const float* __restrict__ Wk_b,
                                                       const float* __restrict__ Wv_w,
                                                       ushort* __restrict__ qwf,
                                                       ushort* __restrict__ kwf,
                                                       ushort* __restrict__ wvtf,
                                                       float* __restrict__ sqb,
                                                       float* __restrict__ skb) {
  int bx = blockIdx.x, tid = threadIdx.x;
  if (bx < 256) {
    int idx = bx * 512 + tid;  // 0..131071
    int e = idx & 7;
    int lane = (idx >> 3) & 63;
    int ks = (idx >> 9) & 7;
    int nt = idx >> 12;
    int r0 = lane & 15, kb = lane >> 4;
    int k = ks * 32 + kb * 8 + e;
    int ch = nt * 16 + r0;
    wvtf[idx] = f2bf(Wv_w[k * 512 + ch]);
  } else if (bx < 272) {
    int idx = (bx - 256) * 512 + tid;  // 0..8191
    int which = idx >> 12;
    int r = idx & 4095;
    int e = r & 7;
    int lane = (r >> 3) & 63;
    int ks = r >> 9;
    int m = lane & 15, kb = lane >> 4;
    int k = ks * 32 + kb * 8 + e;
    float s = 0.f;
    if (m < 8) {
      const float* W = which ? Wk_w : Wq_w;
      const float4* p = reinterpret_cast<const float4*>(W + (size_t)k * 512 + m * 64);
      #pragma unroll
      for (int c4 = 0; c4 < 8; ++c4) {
        float4 x = p[c4];
        s += x.x + x.y + x.z + x.w;
      }
    }
    (which ? kwf : qwf)[r] = f2bf(s);
  } else {
    if (tid < 8) {
      float s = 0.f;
      for (int c = 0; c < 32; ++c) s += Wq_b[tid * 64 + c];
      sqb[tid] = s;
    } else if (tid < 16) {
      int mm = tid - 8;
      float s = 0.f;
      for (int c = 0; c < 32; ++c) s += Wk_b[mm * 64 + c];
      skb[mm] = s;
    }
  }
}

// ---- qk_direct: barrier-free, LDS-free channel sums ----
// wave = one 16-row tile. A-frag direct from global (lane (r0,kb), 8 floats
// per ks), cvt to bf16 in reg, 8 MFMA vs qwf/kwf (L1-hot), scatter 4 outputs.
// q tiles: 11264 (180224 rows), k tiles: 5632. 1056 blocks x 4 waves = 4224
// waves x 4 tiles each.
__global__ __launch_bounds__(256) void qk_direct_kernel(const float* __restrict__ q,
                                                        const float* __restrict__ k,
                                                        const ushort* __restrict__ qwf,
                                                        const ushort* __restrict__ kwf,
                                                        const float* __restrict__ sqb,
                                                        const float* __restrict__ skb,
                                                        float* __restrict__ qsum,
                                                        float* __restrict__ ksumraw) {
  int tid = threadIdx.x;
  int lane = tid & 63;
  int r0 = lane & 15, kb = lane >> 4;
  int wgid = blockIdx.x * 4 + (tid >> 6);  // 0..4223
  const int NQT = 11264, NTOT = 16896;
  for (int tile = wgid; tile < NTOT; tile += 4224) {
    bool isK = tile >= NQT;
    int tt = isK ? tile - NQT : tile;
    const float* src = (isK ? k : q) + (size_t)(tt * 16 + r0) * 256;
    const ushort* wf = isK ? kwf : qwf;
    f32x4 acc = {0.f, 0.f, 0.f, 0.f};
    #pragma unroll
    for (int ks = 0; ks < 8; ++ks) {
      float4 xa = *reinterpret_cast<const float4*>(src + ks * 32 + kb * 8);
      float4 xb = *reinterpret_cast<const float4*>(src + ks * 32 + kb * 8 + 4);
      short8 a;
      a[0] = (short)f2bf(xa.x); a[1] = (short)f2bf(xa.y);
      a[2] = (short)f2bf(xa.z); a[3] = (short)f2bf(xa.w);
      a[4] = (short)f2bf(xb.x); a[5] = (short)f2bf(xb.y);
      a[6] = (short)f2bf(xb.z); a[7] = (short)f2bf(xb.w);
      short8 bf = *reinterpret_cast<const short8*>(wf + (ks * 64 + lane) * 8);
      acc = __builtin_amdgcn_mfma_f32_16x16x32_bf16(a, bf, acc, 0, 0, 0);
    }
    if (r0 < 8) {  // D: col = lane&15 = m, row = kb*4+reg (m89-verified)
      int m = r0;
      float bias = isK ? skb[m] : sqb[m];
      #pragma unroll
      for (int reg = 0; reg < 4; ++reg) {
        int R = tt * 16 + kb * 4 + reg;
        if (!isK) {
          int b = R / 704, rem = R % 704;
          int fo2 = rem / 22, j2 = rem % 22;
          int lf = (fo2 & 3) * 11264 + j2 * 512 + m * 64;
          int t = lf / 1408;
          int s = (lf % 1408) >> 6;
          int h = fo2 >> 2;
          qsum[(((size_t)b * 8 + h) * 32 + t) * 22 + s] = acc[reg] + bias;
        } else {
          int b = R / 352, rem = R % 352;
          int f2 = rem / 22, j2 = rem % 22;
          int lf = (f2 & 1) * 11264 + j2 * 512 + m * 64;
          int floc = lf / 1408;
          int jj = (lf % 1408) >> 6;
          int h = f2 >> 1;
          ksumraw[(((size_t)b * 8 + h) * 16 + floc) * 22 + jj] = acc[reg] + bias;
        }
      }
    }
  }
}

// ---- vproj: MFMA + 4-phase dump/gather (R10/R11-verified body) ----
__global__ __launch_bounds__(512, 2) void vproj_kernel(const float* __restrict__ v,
                                                       const ushort* __restrict__ wvtf,
                                                       const float* __restrict__ Wv_b,
                                                       float* __restrict__ vs_inner,
                                                       float* __restrict__ vtsum) {
  int bh = blockIdx.x;  // 0..2047
  __shared__ float sbuf[6656];  // lA (24.6KB); reused as dump
  ushort* lA = reinterpret_cast<ushort*>(sbuf);
  float* dump = sbuf;
  int tid = threadIdx.x, lane = tid & 63, w = tid >> 6;
  int r0 = lane & 15, kb = lane >> 4;

  STAGE44(v + (size_t)bh * 11264);
  __syncthreads();

  int nt0 = w * 4;
  f32x4 acc[3][4];
  #pragma unroll
  for (int m = 0; m < 3; ++m)
    #pragma unroll
    for (int n = 0; n < 4; ++n) acc[m][n] = (f32x4){0.f, 0.f, 0.f, 0.f};

  #pragma unroll
  for (int ks = 0; ks < 8; ++ks) {
    int go = ((ks * 4 + kb) ^ (r0 & 7)) * 8;
    short8 a0 = *reinterpret_cast<const short8*>(&lA[(r0) * 256 + go]);
    short8 a1 = *reinterpret_cast<const short8*>(&lA[(16 + r0) * 256 + go]);
    short8 a2 = *reinterpret_cast<const short8*>(&lA[(32 + r0) * 256 + go]);
    #pragma unroll
    for (int n = 0; n < 4; ++n) {
      short8 bf = *reinterpret_cast<const short8*>(
          wvtf + ((size_t)((nt0 + n) * 8 + ks) * 64 + lane) * 8);
      acc[0][n] = __builtin_amdgcn_mfma_f32_16x16x32_bf16(bf, a0, acc[0][n], 0, 0, 0);
      acc[1][n] = __builtin_amdgcn_mfma_f32_16x16x32_bf16(bf, a1, acc[1][n], 0, 0, 0);
      acc[2][n] = __builtin_amdgcn_mfma_f32_16x16x32_bf16(bf, a2, acc[2][n], 0, 0, 0);
    }
  }
  __syncthreads();  // lA reads done; sbuf becomes dump

  #pragma unroll
  for (int n = 0; n < 4; ++n) {
    float4 bq = *reinterpret_cast<const float4*>(Wv_b + w * 64 + n * 16 + kb * 4);
    int dbase = tid * 13;
    #pragma unroll
    for (int m = 0; m < 3; ++m) {
      dump[dbase + m * 4 + 0] = acc[m][n][0] + bq.x;
      dump[dbase + m * 4 + 1] = acc[m][n][1] + bq.y;
      dump[dbase + m * 4 + 2] = acc[m][n][2] + bq.z;
      dump[dbase + m * 4 + 3] = acc[m][n][3] + bq.w;
    }
    __syncthreads();
    if (n < 2) {
      if (tid < 256) {
        int f = tid >> 4, rest = tid & 15;
        int kb2 = rest >> 2, reg = rest & 3;
        float s = 0.f;
        #pragma unroll
        for (int u = 0; u < 22; ++u) {
          int fj = f * 22 + u;
          int f2 = (fj >= 176) ? 1 : 0;
          int rem = fj - f2 * 176;
          int j = rem >> 3, ww = rem & 7;
          int vrow = f2 * 22 + j;
          int m = vrow >> 4, rr = vrow & 15;
          s += dump[(ww * 64 + kb2 * 16 + rr) * 13 + m * 4 + reg];
        }
        vs_inner[(size_t)bh * 512 + f * 32 + n * 16 + kb2 * 4 + reg] = s;
      }
    } else {
      if (tid < 352) {
        int jj = tid >> 4, rest = tid & 15;
        int kb2 = rest >> 2, reg = rest & 3;
        float s = 0.f;
        #pragma unroll
        for (int f = 0; f < 16; ++f) {
          int fj = f * 22 + jj;
          int f2 = (fj >= 176) ? 1 : 0;
          int rem = fj - f2 * 176;
          int j = rem >> 3, ww = rem & 7;
          int vrow = f2 * 22 + j;
          int m = vrow >> 4, rr = vrow & 15;
          s += dump[(ww * 64 + kb2 * 16 + rr) * 13 + m * 4 + reg];
        }
        vtsum[(size_t)bh * 704 + jj * 32 + (n - 2) * 16 + kb2 * 4 + reg] = s;
      }
    }
    __syncthreads();
  }
}

// ---- final2: conv_s (k & v) + diag softmax + output, 2 t/block (verified) --
__global__ __launch_bounds__(512, 2) void final2_kernel(const float* __restrict__ qsum,
                                                        const float* __restrict__ ksumraw,
                                                        const float* __restrict__ vs_inner,
                                                        const float* __restrict__ vtsum,
                                                        const int* __restrict__ mask_s,
                                                        const float* __restrict__ csw,
                                                        const float* __restrict__ csb,
                                                        float* __restrict__ out) {
  int blk = blockIdx.x;  // b*16 + tp
  int tp = blk & 15, b = blk >> 4;
  int t0 = tp * 2;
  __shared__ float vtl[8][704];
  __shared__ float vsi[8][16][32];
  __shared__ float kraw[8][16][22];
  __shared__ float ql2[2][8][22];
  __shared__ float klrow[2][8][22];
  __shared__ float vss[2][8][32];
  __shared__ float dg2[2][8][22];
  __shared__ float lcw[2][18];
  __shared__ int msk[484];
  int tid = threadIdx.x;
  size_t bb = (size_t)b;

  {
    const float4* p = reinterpret_cast<const float4*>(vtsum + bb * 5632);
    float4* dst = reinterpret_cast<float4*>(&vtl[0][0]);
    for (int i = tid; i < 1408; i += 512) dst[i] = p[i];
  }
  {
    const float4* p = reinterpret_cast<const float4*>(vs_inner + bb * 4096);
    float4* dst = reinterpret_cast<float4*>(&vsi[0][0][0]);
    for (int i = tid; i < 1024; i += 512) dst[i] = p[i];
  }
  {
    const float4* p = reinterpret_cast<const float4*>(ksumraw + bb * 2816);
    float4* dst = reinterpret_cast<float4*>(&kraw[0][0][0]);
    for (int i = tid; i < 704; i += 512) dst[i] = p[i];
  }
  if (tid < 352) {
    int tt = tid / 176, r = tid % 176;
    int h = r / 22, s = r % 22;
    ql2[tt][h][s] = qsum[((bb * 8 + h) * 32 + t0 + tt) * 22 + s];
  }
  if (tid < 484) msk[tid] = mask_s[tid];
  if (tid < 32) {
    int tt = tid >> 4, f = tid & 15;
    lcw[tt][f] = csw[(t0 + tt) * 16 + f];
  }
  if (tid >= 32 && tid < 34) lcw[tid - 32][16] = csb[t0 + (tid - 32)];
  __syncthreads();

  if (tid < 352) {
    int tt = tid / 176, r = tid % 176;
    int h = r / 22, j = r % 22;
    float a = 32.0f * lcw[tt][16];
    #pragma unroll
    for (int f = 0; f < 16; ++f) a += lcw[tt][f] * kraw[h][f][j];
    klrow[tt][h][j] = a;
  }
  {
    int tt = tid >> 8, r = tid & 255;
    int h = r >> 5, d = r & 31;
    float a = 22.0f * lcw[tt][16];
    #pragma unroll
    for (int f = 0; f < 16; ++f) a += lcw[tt][f] * vsi[h][f][d];
    vss[tt][h][d] = a;
  }
  __syncthreads();

  if (tid < 352) {
    int tt = tid / 176, r = tid % 176;
    int h = r / 22, s = r % 22;
    float qv = ql2[tt][h][s];
    float mx = -3.0e38f;
    #pragma unroll
    for (int u = 0; u < 22; ++u) {
      float av = msk[s * 22 + u] ? qv * klrow[tt][h][u] : NEGV;
      mx = fmaxf(mx, av);
    }
    float den = 0.f;
    #pragma unroll
    for (int u = 0; u < 22; ++u) {
      float av = msk[s * 22 + u] ? qv * klrow[tt][h][u] : NEGV;
      den += expf(av - mx);
    }
    float as = msk[s * 22 + s] ? qv * klrow[tt][h][s] : NEGV;
    dg2[tt][h][s] = expf(as - mx) / den;
  }
  __syncthreads();

  #pragma unroll
  for (int tt = 0; tt < 2; ++tt) {
    float4* ob4 = reinterpret_cast<float4*>(out + (size_t)(b * 32 + t0 + tt) * 11264);
    #pragma unroll
    for (int it = 0; it < 6; ++it) {
      int i4 = tid + it * 512;  // 0..2815
      if (i4 < 2816) {
        int s = i4 >> 7;
        int ch4 = i4 & 127;
        int h = ch4 >> 4;
        int d0 = (ch4 & 15) * 4;
        float4 val;
        if (d0 < 32) {
          float g = dg2[tt][h][s];
          const float* vp = &vss[tt][h][d0];
          val.x = g * vp[0]; val.y = g * vp[1]; val.z = g * vp[2]; val.w = g * vp[3];
        } else {
          const float* tpn = &vtl[h][s * 32 + d0 - 32];
          val.x = tpn[0]; val.y = tpn[1]; val.z = tpn[2]; val.w = tpn[3];
        }
        ob4[i4] = val;
      }
    }
  }
}

extern "C" void kernel_launch(void* const* d_in, const int* in_sizes, int n_in,
                              void* d_out, int out_size, void* d_ws, size_t ws_size,
                              hipStream_t stream) {
  const float* q = (const float*)d_in[0];
  const float* k = (const float*)d_in[1];
  const float* v = (const float*)d_in[2];
  const int* mask_s = (const int*)d_in[3];
  const float* Wq_w = (const float*)d_in[5];
  const float* Wq_b = (const float*)d_in[6];
  const float* Wk_w = (const float*)d_in[7];
  const float* Wk_b = (const float*)d_in[8];
  const float* Wv_w = (const float*)d_in[9];
  const float* Wv_b = (const float*)d_in[10];
  const float* csw = (const float*)d_in[11];
  const float* csb = (const float*)d_in[12];
  float* out = (float*)d_out;

  float* ws = (float*)d_ws;
  float* sqb = ws;                            // 8
  float* skb = ws + 8;                        // 8 -> 16
  ushort* wvtf = (ushort*)(ws + 16);          // 131072 us -> ends f-idx 65552
  ushort* qwf = (ushort*)(ws + 65552);        // 4096 us -> 67600
  ushort* kwf = (ushort*)(ws + 67600);        // 4096 us -> 69648
  float* qsum = ws + 69648;                   // 1441792
  float* ksumraw = qsum + 1441792;            // 720896
  float* vs_inner = ksumraw + 720896;         // 1048576
  float* vtsum = vs_inner + 1048576;          // 1441792

  hipLaunchKernelGGL(prep_all_kernel, dim3(273), dim3(512), 0, stream,
                     Wq_w, Wq_b, Wk_w, Wk_b, Wv_w, qwf, kwf, wvtf, sqb, skb);
  hipLaunchKernelGGL(qk_direct_kernel, dim3(1056), dim3(256), 0, stream,
                     q, k, qwf, kwf, sqb, skb, qsum, ksumraw);
  hipLaunchKernelGGL(vproj_kernel, dim3(2048), dim3(512), 0, stream,
                     v, wvtf, Wv_b, vs_inner, vtsum);
  hipLaunchKernelGGL(final2_kernel, dim3(4096), dim3(512), 0, stream,
                     qsum, ksumraw, vs_inner, vtsum, mask_s, csw, csb, out);
}

// Round 13
// 219.315 us; speedup vs baseline: 1.4305x; 1.2914x over previous
//
#include <hip/hip_runtime.h>

// B=256, F=16, FO=32, J=22, H=8, IN=256, OUT=512, HID=64, HS=32
// Degenerate-einsum analysis:
//   attn_s = qsum (x) ksum  (outer product of channel sums)
//   x_s    = diag(softmax(attn_s)) * (sum_u v_s')
//   x_t    = sum_f v_t  (softmax sums to 1; q_t/k_t/conv_t/mask_t unused)
// Round 13: one compute kernel, heterogeneous interleaved blocks:
//   even bx -> barrier-free qk-direct waves (R12-verified), odd bx -> vproj
//   (R10-verified). Streaming qk blocks keep HBM busy while co-resident
//   vproj blocks barrier/compute. + nontemporal stores for the 369MB output.

#define NEGV (-1000000000.0f)

typedef __attribute__((ext_vector_type(8))) short short8;
typedef __attribute__((ext_vector_type(4))) float f32x4;

__device__ inline ushort f2bf(float f) {
  union { float f; unsigned u; } a;
  a.f = f;
  unsigned u = a.u;
  return (ushort)((u + 0x7FFFu + ((u >> 16) & 1u)) >> 16);  // RNE
}

// stage 44 rows x 256 f32 -> bf16 into lA with granule swizzle gp = gl ^ (row&7)
#define PUTG(g, pa, pb)                                                        \
  {                                                                            \
    int row_ = (g) >> 5, gl_ = (g) & 31;                                       \
    int gp_ = gl_ ^ (row_ & 7);                                                \
    short8 u_;                                                                 \
    u_[0] = (short)f2bf(pa.x); u_[1] = (short)f2bf(pa.y);                      \
    u_[2] = (short)f2bf(pa.z); u_[3] = (short)f2bf(pa.w);                      \
    u_[4] = (short)f2bf(pb.x); u_[5] = (short)f2bf(pb.y);                      \
    u_[6] = (short)f2bf(pb.z); u_[7] = (short)f2bf(pb.w);                      \
    *reinterpret_cast<short8*>(&lA[row_ * 256 + gp_ * 8]) = u_;                \
  }

#define STAGE44(SRCPTR)                                                        \
  {                                                                            \
    const float* vsrc_ = (SRCPTR);                                             \
    int g0 = tid, g1 = tid + 512, g2 = tid + 1024;                             \
    float4 a0 = *reinterpret_cast<const float4*>(vsrc_ + g0 * 8);              \
    float4 b0 = *reinterpret_cast<const float4*>(vsrc_ + g0 * 8 + 4);          \
    float4 a1 = *reinterpret_cast<const float4*>(vsrc_ + g1 * 8);              \
    float4 b1 = *reinterpret_cast<const float4*>(vsrc_ + g1 * 8 + 4);          \
    float4 a2 = {0, 0, 0, 0}, b2 = {0, 0, 0, 0};                               \
    if (g2 < 1408) {                                                           \
      a2 = *reinterpret_cast<const float4*>(vsrc_ + g2 * 8);                   \
      b2 = *reinterpret_cast<const float4*>(vsrc_ + g2 * 8 + 4);               \
    }                                                                          \
    PUTG(g0, a0, b0);                                                          \
    PUTG(g1, a1, b1);                                                          \
    if (g2 < 1408) PUTG(g2, a2, b2);                                           \
    if (tid < 128) {                                                           \
      int g = 1408 + tid;                                                      \
      int row_ = g >> 5, gp_ = (g & 31) ^ (row_ & 7);                          \
      short8 z = {0, 0, 0, 0, 0, 0, 0, 0};                                     \
      *reinterpret_cast<short8*>(&lA[row_ * 256 + gp_ * 8]) = z;               \
    }                                                                          \
  }

// ---------------- prep_all: wvt (0..255) + qkwf (256..271) + prepb (272) ----
__global__ __launch_bounds__(512) void prep_all_kernel(const float* __restrict__ Wq_w,
                                                       const float* __restrict__ Wq_b,
                                                       const float* __restrict__ Wk_w,
                                                       const float* __restrict__ Wk_b,
                                                       const float* __restrict__ Wv_w,
                                                       ushort* __restrict__ qwf,
                                                       ushort* __restrict__ kwf,
                                                       ushort* __restrict__ wvtf,
                                                       float* __restrict__ sqb,
                                                       float* __restrict__ skb) {
  int bx = blockIdx.x, tid = threadIdx.x;
  if (bx < 256) {
    int idx = bx * 512 + tid;  // 0..131071
    int e = idx & 7;
    int lane = (idx >> 3) & 63;
    int ks = (idx >> 9) & 7;
    int nt = idx >> 12;
    int r0 = lane & 15, kb = lane >> 4;
    int k = ks * 32 + kb * 8 + e;
    int ch = nt * 16 + r0;
    wvtf[idx] = f2bf(Wv_w[k * 512 + ch]);
  } else if (bx < 272) {
    int idx = (bx - 256) * 512 + tid;  // 0..8191
    int which = idx >> 12;
    int r = idx & 4095;
    int e = r & 7;
    int lane = (r >> 3) & 63;
    int ks = r >> 9;
    int m = lane & 15, kb = lane >> 4;
    int k = ks * 32 + kb * 8 + e;
    float s = 0.f;
    if (m < 8) {
      const float* W = which ? Wk_w : Wq_w;
      const float4* p = reinterpret_cast<const float4*>(W + (size_t)k * 512 + m * 64);
      #pragma unroll
      for (int c4 = 0; c4 < 8; ++c4) {
        float4 x = p[c4];
        s += x.x + x.y + x.z + x.w;
      }
    }
    (which ? kwf : qwf)[r] = f2bf(s);
  } else {
    if (tid < 8) {
      float s = 0.f;
      for (int c = 0; c < 32; ++c) s += Wq_b[tid * 64 + c];
      sqb[tid] = s;
    } else if (tid < 16) {
      int mm = tid - 8;
      float s = 0.f;
      for (int c = 0; c < 32; ++c) s += Wk_b[mm * 64 + c];
      skb[mm] = s;
    }
  }
}

// ---- fused2: interleaved heterogeneous blocks ----
// even bx (<4096) + bx>=4096 : qk-direct groups (8 waves, 1 tile/wave, no LDS,
//   no barrier). odd bx (<4096): vproj bh = bx>>1 (stage->MFMA->dump/gather).
__global__ __launch_bounds__(512, 2) void fused2_kernel(const float* __restrict__ q,
                                                        const float* __restrict__ k,
                                                        const float* __restrict__ v,
                                                        const ushort* __restrict__ qwf,
                                                        const ushort* __restrict__ kwf,
                                                        const ushort* __restrict__ wvtf,
                                                        const float* __restrict__ sqb,
                                                        const float* __restrict__ skb,
                                                        const float* __restrict__ Wv_b,
                                                        float* __restrict__ qsum,
                                                        float* __restrict__ ksumraw,
                                                        float* __restrict__ vs_inner,
                                                        float* __restrict__ vtsum) {
  int bx = blockIdx.x;
  __shared__ float sbuf[6656];  // vproj branch only: lA (24.6KB) then dump
  int tid = threadIdx.x, lane = tid & 63, w = tid >> 6;
  int r0 = lane & 15, kb = lane >> 4;

  bool isQK = (bx >= 4096) || !(bx & 1);
  if (isQK) {
    // ---- qk-direct (R12-verified body), 1 tile per wave ----
    int gid = (bx >= 4096) ? (2048 + bx - 4096) : (bx >> 1);  // 0..2111
    int tile = gid * 8 + w;  // 0..16895
    bool isK = tile >= 11264;
    int tt = isK ? tile - 11264 : tile;
    const float* src = (isK ? k : q) + (size_t)(tt * 16 + r0) * 256;
    const ushort* wf = isK ? kwf : qwf;
    f32x4 acc = {0.f, 0.f, 0.f, 0.f};
    #pragma unroll
    for (int ks = 0; ks < 8; ++ks) {
      f32x4 xa = __builtin_nontemporal_load(
          reinterpret_cast<const f32x4*>(src + ks * 32 + kb * 8));
      f32x4 xb = __builtin_nontemporal_load(
          reinterpret_cast<const f32x4*>(src + ks * 32 + kb * 8 + 4));
      short8 a;
      a[0] = (short)f2bf(xa.x); a[1] = (short)f2bf(xa.y);
      a[2] = (short)f2bf(xa.z); a[3] = (short)f2bf(xa.w);
      a[4] = (short)f2bf(xb.x); a[5] = (short)f2bf(xb.y);
      a[6] = (short)f2bf(xb.z); a[7] = (short)f2bf(xb.w);
      short8 bf = *reinterpret_cast<const short8*>(wf + (ks * 64 + lane) * 8);
      acc = __builtin_amdgcn_mfma_f32_16x16x32_bf16(a, bf, acc, 0, 0, 0);
    }
    if (r0 < 8) {  // D: col = lane&15 = m, row = kb*4+reg (m89-verified)
      int m = r0;
      float bias = isK ? skb[m] : sqb[m];
      #pragma unroll
      for (int reg = 0; reg < 4; ++reg) {
        int R = tt * 16 + kb * 4 + reg;
        if (!isK) {
          int b = R / 704, rem = R % 704;
          int fo2 = rem / 22, j2 = rem % 22;
          int lf = (fo2 & 3) * 11264 + j2 * 512 + m * 64;
          int t = lf / 1408;
          int s = (lf % 1408) >> 6;
          int h = fo2 >> 2;
          qsum[(((size_t)b * 8 + h) * 32 + t) * 22 + s] = acc[reg] + bias;
        } else {
          int b = R / 352, rem = R % 352;
          int f2 = rem / 22, j2 = rem % 22;
          int lf = (f2 & 1) * 11264 + j2 * 512 + m * 64;
          int floc = lf / 1408;
          int jj = (lf % 1408) >> 6;
          int h = f2 >> 1;
          ksumraw[(((size_t)b * 8 + h) * 16 + floc) * 22 + jj] = acc[reg] + bias;
        }
      }
    }
  } else {
    // ---- vproj (R10-verified body) ----
    int bh = bx >> 1;  // 0..2047
    ushort* lA = reinterpret_cast<ushort*>(sbuf);
    float* dump = sbuf;
    STAGE44(v + (size_t)bh * 11264);
    __syncthreads();

    int nt0 = w * 4;
    f32x4 acc[3][4];
    #pragma unroll
    for (int m = 0; m < 3; ++m)
      #pragma unroll
      for (int n = 0; n < 4; ++n) acc[m][n] = (f32x4){0.f, 0.f, 0.f, 0.f};

    #pragma unroll
    for (int ks = 0; ks < 8; ++ks) {
      int go = ((ks * 4 + kb) ^ (r0 & 7)) * 8;
      short8 a0 = *reinterpret_cast<const short8*>(&lA[(r0) * 256 + go]);
      short8 a1 = *reinterpret_cast<const short8*>(&lA[(16 + r0) * 256 + go]);
      short8 a2 = *reinterpret_cast<const short8*>(&lA[(32 + r0) * 256 + go]);
      #pragma unroll
      for (int n = 0; n < 4; ++n) {
        short8 bf = *reinterpret_cast<const short8*>(
            wvtf + ((size_t)((nt0 + n) * 8 + ks) * 64 + lane) * 8);
        acc[0][n] = __builtin_amdgcn_mfma_f32_16x16x32_bf16(bf, a0, acc[0][n], 0, 0, 0);
        acc[1][n] = __builtin_amdgcn_mfma_f32_16x16x32_bf16(bf, a1, acc[1][n], 0, 0, 0);
        acc[2][n] = __builtin_amdgcn_mfma_f32_16x16x32_bf16(bf, a2, acc[2][n], 0, 0, 0);
      }
    }
    __syncthreads();  // lA reads done; sbuf becomes dump

    #pragma unroll
    for (int n = 0; n < 4; ++n) {
      float4 bq = *reinterpret_cast<const float4*>(Wv_b + w * 64 + n * 16 + kb * 4);
      int dbase = tid * 13;
      #pragma unroll
      for (int m = 0; m < 3; ++m) {
        dump[dbase + m * 4 + 0] = acc[m][n][0] + bq.x;
        dump[dbase + m * 4 + 1] = acc[m][n][1] + bq.y;
        dump[dbase + m * 4 + 2] = acc[m][n][2] + bq.z;
        dump[dbase + m * 4 + 3] = acc[m][n][3] + bq.w;
      }
      __syncthreads();
      if (n < 2) {
        if (tid < 256) {
          int f = tid >> 4, rest = tid & 15;
          int kb2 = rest >> 2, reg = rest & 3;
          float s = 0.f;
          #pragma unroll
          for (int u = 0; u < 22; ++u) {
            int fj = f * 22 + u;
            int f2 = (fj >= 176) ? 1 : 0;
            int rem = fj - f2 * 176;
            int j = rem >> 3, ww = rem & 7;
            int vrow = f2 * 22 + j;
            int m = vrow >> 4, rr = vrow & 15;
            s += dump[(ww * 64 + kb2 * 16 + rr) * 13 + m * 4 + reg];
          }
          vs_inner[(size_t)bh * 512 + f * 32 + n * 16 + kb2 * 4 + reg] = s;
        }
      } else {
        if (tid < 352) {
          int jj = tid >> 4, rest = tid & 15;
          int kb2 = rest >> 2, reg = rest & 3;
          float s = 0.f;
          #pragma unroll
          for (int f = 0; f < 16; ++f) {
            int fj = f * 22 + jj;
            int f2 = (fj >= 176) ? 1 : 0;
            int rem = fj - f2 * 176;
            int j = rem >> 3, ww = rem & 7;
            int vrow = f2 * 22 + j;
            int m = vrow >> 4, rr = vrow & 15;
            s += dump[(ww * 64 + kb2 * 16 + rr) * 13 + m * 4 + reg];
          }
          vtsum[(size_t)bh * 704 + jj * 32 + (n - 2) * 16 + kb2 * 4 + reg] = s;
        }
      }
      __syncthreads();
    }
  }
}

// ---- final2: conv_s (k & v) + diag softmax + output, 2 t/block ----
// R10-verified body + nontemporal output stores (keep L2 for per-b staging).
__global__ __launch_bounds__(512, 2) void final2_kernel(const float* __restrict__ qsum,
                                                        const float* __restrict__ ksumraw,
                                                        const float* __restrict__ vs_inner,
                                                        const float* __restrict__ vtsum,
                                                        const int* __restrict__ mask_s,
                                                        const float* __restrict__ csw,
                                                        const float* __restrict__ csb,
                                                        float* __restrict__ out) {
  int blk = blockIdx.x;  // b*16 + tp
  int tp = blk & 15, b = blk >> 4;
  int t0 = tp * 2;
  __shared__ float vtl[8][704];
  __shared__ float vsi[8][16][32];
  __shared__ float kraw[8][16][22];
  __shared__ float ql2[2][8][22];
  __shared__ float klrow[2][8][22];
  __shared__ float vss[2][8][32];
  __shared__ float dg2[2][8][22];
  __shared__ float lcw[2][18];
  __shared__ int msk[484];
  int tid = threadIdx.x;
  size_t bb = (size_t)b;

  {
    const float4* p = reinterpret_cast<const float4*>(vtsum + bb * 5632);
    float4* dst = reinterpret_cast<float4*>(&vtl[0][0]);
    for (int i = tid; i < 1408; i += 512) dst[i] = p[i];
  }
  {
    const float4* p = reinterpret_cast<const float4*>(vs_inner + bb * 4096);
    float4* dst = reinterpret_cast<float4*>(&vsi[0][0][0]);
    for (int i = tid; i < 1024; i += 512) dst[i] = p[i];
  }
  {
    const float4* p = reinterpret_cast<const float4*>(ksumraw + bb * 2816);
    float4* dst = reinterpret_cast<float4*>(&kraw[0][0][0]);
    for (int i = tid; i < 704; i += 512) dst[i] = p[i];
  }
  if (tid < 352) {
    int tt = tid / 176, r = tid % 176;
    int h = r / 22, s = r % 22;
    ql2[tt][h][s] = qsum[((bb * 8 + h) * 32 + t0 + tt) * 22 + s];
  }
  if (tid < 484) msk[tid] = mask_s[tid];
  if (tid < 32) {
    int tt = tid >> 4, f = tid & 15;
    lcw[tt][f] = csw[(t0 + tt) * 16 + f];
  }
  if (tid >= 32 && tid < 34) lcw[tid - 32][16] = csb[t0 + (tid - 32)];
  __syncthreads();

  if (tid < 352) {
    int tt = tid / 176, r = tid % 176;
    int h = r / 22, j = r % 22;
    float a = 32.0f * lcw[tt][16];
    #pragma unroll
    for (int f = 0; f < 16; ++f) a += lcw[tt][f] * kraw[h][f][j];
    klrow[tt][h][j] = a;
  }
  {
    int tt = tid >> 8, r = tid & 255;
    int h = r >> 5, d = r & 31;
    float a = 22.0f * lcw[tt][16];
    #pragma unroll
    for (int f = 0; f < 16; ++f) a += lcw[tt][f] * vsi[h][f][d];
    vss[tt][h][d] = a;
  }
  __syncthreads();

  if (tid < 352) {
    int tt = tid / 176, r = tid % 176;
    int h = r / 22, s = r % 22;
    float qv = ql2[tt][h][s];
    float mx = -3.0e38f;
    #pragma unroll
    for (int u = 0; u < 22; ++u) {
      float av = msk[s * 22 + u] ? qv * klrow[tt][h][u] : NEGV;
      mx = fmaxf(mx, av);
    }
    float den = 0.f;
    #pragma unroll
    for (int u = 0; u < 22; ++u) {
      float av = msk[s * 22 + u] ? qv * klrow[tt][h][u] : NEGV;
      den += expf(av - mx);
    }
    float as = msk[s * 22 + s] ? qv * klrow[tt][h][s] : NEGV;
    dg2[tt][h][s] = expf(as - mx) / den;
  }
  __syncthreads();

  #pragma unroll
  for (int tt = 0; tt < 2; ++tt) {
    f32x4* ob4 = reinterpret_cast<f32x4*>(out + (size_t)(b * 32 + t0 + tt) * 11264);
    #pragma unroll
    for (int it = 0; it < 6; ++it) {
      int i4 = tid + it * 512;  // 0..2815
      if (i4 < 2816) {
        int s = i4 >> 7;
        int ch4 = i4 & 127;
        int h = ch4 >> 4;
        int d0 = (ch4 & 15) * 4;
        f32x4 val;
        if (d0 < 32) {
          float g = dg2[tt][h][s];
          const float* vp = &vss[tt][h][d0];
          val[0] = g * vp[0]; val[1] = g * vp[1]; val[2] = g * vp[2]; val[3] = g * vp[3];
        } else {
          const float* tpn = &vtl[h][s * 32 + d0 - 32];
          val[0] = tpn[0]; val[1] = tpn[1]; val[2] = tpn[2]; val[3] = tpn[3];
        }
        __builtin_nontemporal_store(val, &ob4[i4]);
      }
    }
  }
}

extern "C" void kernel_launch(void* const* d_in, const int* in_sizes, int n_in,
                              void* d_out, int out_size, void* d_ws, size_t ws_size,
                              hipStream_t stream) {
  const float* q = (const float*)d_in[0];
  const float* k = (const float*)d_in[1];
  const float* v = (const float*)d_in[2];
  const int* mask_s = (const int*)d_in[3];
  const float* Wq_w = (const float*)d_in[5];
  const float* Wq_b = (const float*)d_in[6];
  const float* Wk_w = (const float*)d_in[7];
  const float* Wk_b = (const float*)d_in[8];
  const float* Wv_w = (const float*)d_in[9];
  const float* Wv_b = (const float*)d_in[10];
  const float* csw = (const float*)d_in[11];
  const float* csb = (const float*)d_in[12];
  float* out = (float*)d_out;

  float* ws = (float*)d_ws;
  float* sqb = ws;                            // 8
  float* skb = ws + 8;                        // 8 -> 16
  ushort* wvtf = (ushort*)(ws + 16);          // 131072 us -> ends f-idx 65552
  ushort* qwf = (ushort*)(ws + 65552);        // 4096 us -> 67600
  ushort* kwf = (ushort*)(ws + 67600);        // 4096 us -> 69648
  float* qsum = ws + 69648;                   // 1441792
  float* ksumraw = qsum + 1441792;            // 720896
  float* vs_inner = ksumraw + 720896;         // 1048576
  float* vtsum = vs_inner + 1048576;          // 1441792

  hipLaunchKernelGGL(prep_all_kernel, dim3(273), dim3(512), 0, stream,
                     Wq_w, Wq_b, Wk_w, Wk_b, Wv_w, qwf, kwf, wvtf, sqb, skb);
  hipLaunchKernelGGL(fused2_kernel, dim3(4160), dim3(512), 0, stream,
                     q, k, v, qwf, kwf, wvtf, sqb, skb, Wv_b,
                     qsum, ksumraw, vs_inner, vtsum);
  hipLaunchKernelGGL(final2_kernel, dim3(4096), dim3(512), 0, stream,
                     qsum, ksumraw, vs_inner, vtsum, mask_s, csw, csb, out);
}

// Round 14
// 215.605 us; speedup vs baseline: 1.4551x; 1.0172x over previous
//
#include <hip/hip_runtime.h>

// B=256, F=16, FO=32, J=22, H=8, IN=256, OUT=512, HID=64, HS=32
// Degenerate-einsum analysis:
//   attn_s = qsum (x) ksum  (outer product of channel sums)
//   x_s    = diag(softmax(attn_s)) * (sum_u v_s')
//   x_t    = sum_f v_t  (softmax sums to 1; q_t/k_t/conv_t/mask_t unused)
// Round 14 (two surgical edits on R13's 219us):
//   1. final2 block reindex b=blk&255 -> all 16 blocks sharing batch b land on
//      one XCD (same dispatch_id mod 8) -> per-b staging fetched once per XCD
//      instead of 8x (~100MB HBM saved).
//   2. vproj STAGE44 v-loads nontemporal (v read once; keep L2 for wvtf/qwf).

#define NEGV (-1000000000.0f)

typedef __attribute__((ext_vector_type(8))) short short8;
typedef __attribute__((ext_vector_type(4))) float f32x4;

__device__ inline ushort f2bf(float f) {
  union { float f; unsigned u; } a;
  a.f = f;
  unsigned u = a.u;
  return (ushort)((u + 0x7FFFu + ((u >> 16) & 1u)) >> 16);  // RNE
}

// stage 44 rows x 256 f32 -> bf16 into lA with granule swizzle gp = gl ^ (row&7)
#define PUTG(g, pa, pb)                                                        \
  {                                                                            \
    int row_ = (g) >> 5, gl_ = (g) & 31;                                       \
    int gp_ = gl_ ^ (row_ & 7);                                                \
    short8 u_;                                                                 \
    u_[0] = (short)f2bf(pa[0]); u_[1] = (short)f2bf(pa[1]);                    \
    u_[2] = (short)f2bf(pa[2]); u_[3] = (short)f2bf(pa[3]);                    \
    u_[4] = (short)f2bf(pb[0]); u_[5] = (short)f2bf(pb[1]);                    \
    u_[6] = (short)f2bf(pb[2]); u_[7] = (short)f2bf(pb[3]);                    \
    *reinterpret_cast<short8*>(&lA[row_ * 256 + gp_ * 8]) = u_;                \
  }

#define STAGE44_NT(SRCPTR)                                                     \
  {                                                                            \
    const float* vsrc_ = (SRCPTR);                                             \
    int g0 = tid, g1 = tid + 512, g2 = tid + 1024;                             \
    f32x4 a0 = __builtin_nontemporal_load(                                     \
        reinterpret_cast<const f32x4*>(vsrc_ + g0 * 8));                       \
    f32x4 b0 = __builtin_nontemporal_load(                                     \
        reinterpret_cast<const f32x4*>(vsrc_ + g0 * 8 + 4));                   \
    f32x4 a1 = __builtin_nontemporal_load(                                     \
        reinterpret_cast<const f32x4*>(vsrc_ + g1 * 8));                       \
    f32x4 b1 = __builtin_nontemporal_load(                                     \
        reinterpret_cast<const f32x4*>(vsrc_ + g1 * 8 + 4));                   \
    f32x4 a2 = {0, 0, 0, 0}, b2 = {0, 0, 0, 0};                                \
    if (g2 < 1408) {                                                           \
      a2 = __builtin_nontemporal_load(                                         \
          reinterpret_cast<const f32x4*>(vsrc_ + g2 * 8));                     \
      b2 = __builtin_nontemporal_load(                                         \
          reinterpret_cast<const f32x4*>(vsrc_ + g2 * 8 + 4));                 \
    }                                                                          \
    PUTG(g0, a0, b0);                                                          \
    PUTG(g1, a1, b1);                                                          \
    if (g2 < 1408) PUTG(g2, a2, b2);                                           \
    if (tid < 128) {                                                           \
      int g = 1408 + tid;                                                      \
      int row_ = g >> 5, gp_ = (g & 31) ^ (row_ & 7);                          \
      short8 z = {0, 0, 0, 0, 0, 0, 0, 0};                                     \
      *reinterpret_cast<short8*>(&lA[row_ * 256 + gp_ * 8]) = z;               \
    }                                                                          \
  }

// ---------------- prep_all: wvt (0..255) + qkwf (256..271) + prepb (272) ----
__global__ __launch_bounds__(512) void prep_all_kernel(const float* __restrict__ Wq_w,
                                                       const float* __restrict__ Wq_b,
                                                       const float* __restrict__ Wk_w,
                                                       const float* __restrict__ Wk_b,
                                                       const float* __restrict__ Wv_w,
                                                       ushort* __restrict__ qwf,
                                                       ushort* __restrict__ kwf,
                                                       ushort* __restrict__ wvtf,
                                                       float* __restrict__ sqb,
                                                       float* __restrict__ skb) {
  int bx = blockIdx.x, tid = threadIdx.x;
  if (bx < 256) {
    int idx = bx * 512 + tid;  // 0..131071
    int e = idx & 7;
    int lane = (idx >> 3) & 63;
    int ks = (idx >> 9) & 7;
    int nt = idx >> 12;
    int r0 = lane & 15, kb = lane >> 4;
    int k = ks * 32 + kb * 8 + e;
    int ch = nt * 16 + r0;
    wvtf[idx] = f2bf(Wv_w[k * 512 + ch]);
  } else if (bx < 272) {
    int idx = (bx - 256) * 512 + tid;  // 0..8191
    int which = idx >> 12;
    int r = idx & 4095;
    int e = r & 7;
    int lane = (r >> 3) & 63;
    int ks = r >> 9;
    int m = lane & 15, kb = lane >> 4;
    int k = ks * 32 + kb * 8 + e;
    float s = 0.f;
    if (m < 8) {
      const float* W = which ? Wk_w : Wq_w;
      const float4* p = reinterpret_cast<const float4*>(W + (size_t)k * 512 + m * 64);
      #pragma unroll
      for (int c4 = 0; c4 < 8; ++c4) {
        float4 x = p[c4];
        s += x.x + x.y + x.z + x.w;
      }
    }
    (which ? kwf : qwf)[r] = f2bf(s);
  } else {
    if (tid < 8) {
      float s = 0.f;
      for (int c = 0; c < 32; ++c) s += Wq_b[tid * 64 + c];
      sqb[tid] = s;
    } else if (tid < 16) {
      int mm = tid - 8;
      float s = 0.f;
      for (int c = 0; c < 32; ++c) s += Wk_b[mm * 64 + c];
      skb[mm] = s;
    }
  }
}

// ---- fused2: interleaved heterogeneous blocks (R13-verified) ----
__global__ __launch_bounds__(512, 2) void fused2_kernel(const float* __restrict__ q,
                                                        const float* __restrict__ k,
                                                        const float* __restrict__ v,
                                                        const ushort* __restrict__ qwf,
                                                        const ushort* __restrict__ kwf,
                                                        const ushort* __restrict__ wvtf,
                                                        const float* __restrict__ sqb,
                                                        const float* __restrict__ skb,
                                                        const float* __restrict__ Wv_b,
                                                        float* __restrict__ qsum,
                                                        float* __restrict__ ksumraw,
                                                        float* __restrict__ vs_inner,
                                                        float* __restrict__ vtsum) {
  int bx = blockIdx.x;
  __shared__ float sbuf[6656];  // vproj branch only: lA (24.6KB) then dump
  int tid = threadIdx.x, lane = tid & 63, w = tid >> 6;
  int r0 = lane & 15, kb = lane >> 4;

  bool isQK = (bx >= 4096) || !(bx & 1);
  if (isQK) {
    // ---- qk-direct (R12-verified body), 1 tile per wave ----
    int gid = (bx >= 4096) ? (2048 + bx - 4096) : (bx >> 1);  // 0..2111
    int tile = gid * 8 + w;  // 0..16895
    bool isK = tile >= 11264;
    int tt = isK ? tile - 11264 : tile;
    const float* src = (isK ? k : q) + (size_t)(tt * 16 + r0) * 256;
    const ushort* wf = isK ? kwf : qwf;
    f32x4 acc = {0.f, 0.f, 0.f, 0.f};
    #pragma unroll
    for (int ks = 0; ks < 8; ++ks) {
      f32x4 xa = __builtin_nontemporal_load(
          reinterpret_cast<const f32x4*>(src + ks * 32 + kb * 8));
      f32x4 xb = __builtin_nontemporal_load(
          reinterpret_cast<const f32x4*>(src + ks * 32 + kb * 8 + 4));
      short8 a;
      a[0] = (short)f2bf(xa[0]); a[1] = (short)f2bf(xa[1]);
      a[2] = (short)f2bf(xa[2]); a[3] = (short)f2bf(xa[3]);
      a[4] = (short)f2bf(xb[0]); a[5] = (short)f2bf(xb[1]);
      a[6] = (short)f2bf(xb[2]); a[7] = (short)f2bf(xb[3]);
      short8 bf = *reinterpret_cast<const short8*>(wf + (ks * 64 + lane) * 8);
      acc = __builtin_amdgcn_mfma_f32_16x16x32_bf16(a, bf, acc, 0, 0, 0);
    }
    if (r0 < 8) {  // D: col = lane&15 = m, row = kb*4+reg (m89-verified)
      int m = r0;
      float bias = isK ? skb[m] : sqb[m];
      #pragma unroll
      for (int reg = 0; reg < 4; ++reg) {
        int R = tt * 16 + kb * 4 + reg;
        if (!isK) {
          int b = R / 704, rem = R % 704;
          int fo2 = rem / 22, j2 = rem % 22;
          int lf = (fo2 & 3) * 11264 + j2 * 512 + m * 64;
          int t = lf / 1408;
          int s = (lf % 1408) >> 6;
          int h = fo2 >> 2;
          qsum[(((size_t)b * 8 + h) * 32 + t) * 22 + s] = acc[reg] + bias;
        } else {
          int b = R / 352, rem = R % 352;
          int f2 = rem / 22, j2 = rem % 22;
          int lf = (f2 & 1) * 11264 + j2 * 512 + m * 64;
          int floc = lf / 1408;
          int jj = (lf % 1408) >> 6;
          int h = f2 >> 1;
          ksumraw[(((size_t)b * 8 + h) * 16 + floc) * 22 + jj] = acc[reg] + bias;
        }
      }
    }
  } else {
    // ---- vproj (R10-verified body, nt v-loads) ----
    int bh = bx >> 1;  // 0..2047
    ushort* lA = reinterpret_cast<ushort*>(sbuf);
    float* dump = sbuf;
    STAGE44_NT(v + (size_t)bh * 11264);
    __syncthreads();

    int nt0 = w * 4;
    f32x4 acc[3][4];
    #pragma unroll
    for (int m = 0; m < 3; ++m)
      #pragma unroll
      for (int n = 0; n < 4; ++n) acc[m][n] = (f32x4){0.f, 0.f, 0.f, 0.f};

    #pragma unroll
    for (int ks = 0; ks < 8; ++ks) {
      int go = ((ks * 4 + kb) ^ (r0 & 7)) * 8;
      short8 a0 = *reinterpret_cast<const short8*>(&lA[(r0) * 256 + go]);
      short8 a1 = *reinterpret_cast<const short8*>(&lA[(16 + r0) * 256 + go]);
      short8 a2 = *reinterpret_cast<const short8*>(&lA[(32 + r0) * 256 + go]);
      #pragma unroll
      for (int n = 0; n < 4; ++n) {
        short8 bf = *reinterpret_cast<const short8*>(
            wvtf + ((size_t)((nt0 + n) * 8 + ks) * 64 + lane) * 8);
        acc[0][n] = __builtin_amdgcn_mfma_f32_16x16x32_bf16(bf, a0, acc[0][n], 0, 0, 0);
        acc[1][n] = __builtin_amdgcn_mfma_f32_16x16x32_bf16(bf, a1, acc[1][n], 0, 0, 0);
        acc[2][n] = __builtin_amdgcn_mfma_f32_16x16x32_bf16(bf, a2, acc[2][n], 0, 0, 0);
      }
    }
    __syncthreads();  // lA reads done; sbuf becomes dump

    #pragma unroll
    for (int n = 0; n < 4; ++n) {
      float4 bq = *reinterpret_cast<const float4*>(Wv_b + w * 64 + n * 16 + kb * 4);
      int dbase = tid * 13;
      #pragma unroll
      for (int m = 0; m < 3; ++m) {
        dump[dbase + m * 4 + 0] = acc[m][n][0] + bq.x;
        dump[dbase + m * 4 + 1] = acc[m][n][1] + bq.y;
        dump[dbase + m * 4 + 2] = acc[m][n][2] + bq.z;
        dump[dbase + m * 4 + 3] = acc[m][n][3] + bq.w;
      }
      __syncthreads();
      if (n < 2) {
        if (tid < 256) {
          int f = tid >> 4, rest = tid & 15;
          int kb2 = rest >> 2, reg = rest & 3;
          float s = 0.f;
          #pragma unroll
          for (int u = 0; u < 22; ++u) {
            int fj = f * 22 + u;
            int f2 = (fj >= 176) ? 1 : 0;
            int rem = fj - f2 * 176;
            int j = rem >> 3, ww = rem & 7;
            int vrow = f2 * 22 + j;
            int m = vrow >> 4, rr = vrow & 15;
            s += dump[(ww * 64 + kb2 * 16 + rr) * 13 + m * 4 + reg];
          }
          vs_inner[(size_t)bh * 512 + f * 32 + n * 16 + kb2 * 4 + reg] = s;
        }
      } else {
        if (tid < 352) {
          int jj = tid >> 4, rest = tid & 15;
          int kb2 = rest >> 2, reg = rest & 3;
          float s = 0.f;
          #pragma unroll
          for (int f = 0; f < 16; ++f) {
            int fj = f * 22 + jj;
            int f2 = (fj >= 176) ? 1 : 0;
            int rem = fj - f2 * 176;
            int j = rem >> 3, ww = rem & 7;
            int vrow = f2 * 22 + j;
            int m = vrow >> 4, rr = vrow & 15;
            s += dump[(ww * 64 + kb2 * 16 + rr) * 13 + m * 4 + reg];
          }
          vtsum[(size_t)bh * 704 + jj * 32 + (n - 2) * 16 + kb2 * 4 + reg] = s;
        }
      }
      __syncthreads();
    }
  }
}

// ---- final2: conv_s (k & v) + diag softmax + output, 2 t/block ----
// R13-verified body; block reindex b=blk&255 (same-b blocks -> same XCD).
__global__ __launch_bounds__(512, 2) void final2_kernel(const float* __restrict__ qsum,
                                                        const float* __restrict__ ksumraw,
                                                        const float* __restrict__ vs_inner,
                                                        const float* __restrict__ vtsum,
                                                        const int* __restrict__ mask_s,
                                                        const float* __restrict__ csw,
                                                        const float* __restrict__ csb,
                                                        float* __restrict__ out) {
  int blk = blockIdx.x;
  int b = blk & 255, tp = blk >> 8;  // XCD-dedup reindex: same b -> same (blk mod 8)
  int t0 = tp * 2;
  __shared__ float vtl[8][704];
  __shared__ float vsi[8][16][32];
  __shared__ float kraw[8][16][22];
  __shared__ float ql2[2][8][22];
  __shared__ float klrow[2][8][22];
  __shared__ float vss[2][8][32];
  __shared__ float dg2[2][8][22];
  __shared__ float lcw[2][18];
  __shared__ int msk[484];
  int tid = threadIdx.x;
  size_t bb = (size_t)b;

  {
    const float4* p = reinterpret_cast<const float4*>(vtsum + bb * 5632);
    float4* dst = reinterpret_cast<float4*>(&vtl[0][0]);
    for (int i = tid; i < 1408; i += 512) dst[i] = p[i];
  }
  {
    const float4* p = reinterpret_cast<const float4*>(vs_inner + bb * 4096);
    float4* dst = reinterpret_cast<float4*>(&vsi[0][0][0]);
    for (int i = tid; i < 1024; i += 512) dst[i] = p[i];
  }
  {
    const float4* p = reinterpret_cast<const float4*>(ksumraw + bb * 2816);
    float4* dst = reinterpret_cast<float4*>(&kraw[0][0][0]);
    for (int i = tid; i < 704; i += 512) dst[i] = p[i];
  }
  if (tid < 352) {
    int tt = tid / 176, r = tid % 176;
    int h = r / 22, s = r % 22;
    ql2[tt][h][s] = qsum[((bb * 8 + h) * 32 + t0 + tt) * 22 + s];
  }
  if (tid < 484) msk[tid] = mask_s[tid];
  if (tid < 32) {
    int tt = tid >> 4, f = tid & 15;
    lcw[tt][f] = csw[(t0 + tt) * 16 + f];
  }
  if (tid >= 32 && tid < 34) lcw[tid - 32][16] = csb[t0 + (tid - 32)];
  __syncthreads();

  if (tid < 352) {
    int tt = tid / 176, r = tid % 176;
    int h = r / 22, j = r % 22;
    float a = 32.0f * lcw[tt][16];
    #pragma unroll
    for (int f = 0; f < 16; ++f) a += lcw[tt][f] * kraw[h][f][j];
    klrow[tt][h][j] = a;
  }
  {
    int tt = tid >> 8, r = tid & 255;
    int h = r >> 5, d = r & 31;
    float a = 22.0f * lcw[tt][16];
    #pragma unroll
    for (int f = 0; f < 16; ++f) a += lcw[tt][f] * vsi[h][f][d];
    vss[tt][h][d] = a;
  }
  __syncthreads();

  if (tid < 352) {
    int tt = tid / 176, r = tid % 176;
    int h = r / 22, s = r % 22;
    float qv = ql2[tt][h][s];
    float mx = -3.0e38f;
    #pragma unroll
    for (int u = 0; u < 22; ++u) {
      float av = msk[s * 22 + u] ? qv * klrow[tt][h][u] : NEGV;
      mx = fmaxf(mx, av);
    }
    float den = 0.f;
    #pragma unroll
    for (int u = 0; u < 22; ++u) {
      float av = msk[s * 22 + u] ? qv * klrow[tt][h][u] : NEGV;
      den += expf(av - mx);
    }
    float as = msk[s * 22 + s] ? qv * klrow[tt][h][s] : NEGV;
    dg2[tt][h][s] = expf(as - mx) / den;
  }
  __syncthreads();

  #pragma unroll
  for (int tt = 0; tt < 2; ++tt) {
    f32x4* ob4 = reinterpret_cast<f32x4*>(out + (size_t)(b * 32 + t0 + tt) * 11264);
    #pragma unroll
    for (int it = 0; it < 6; ++it) {
      int i4 = tid + it * 512;  // 0..2815
      if (i4 < 2816) {
        int s = i4 >> 7;
        int ch4 = i4 & 127;
        int h = ch4 >> 4;
        int d0 = (ch4 & 15) * 4;
        f32x4 val;
        if (d0 < 32) {
          float g = dg2[tt][h][s];
          const float* vp = &vss[tt][h][d0];
          val[0] = g * vp[0]; val[1] = g * vp[1]; val[2] = g * vp[2]; val[3] = g * vp[3];
        } else {
          const float* tpn = &vtl[h][s * 32 + d0 - 32];
          val[0] = tpn[0]; val[1] = tpn[1]; val[2] = tpn[2]; val[3] = tpn[3];
        }
        __builtin_nontemporal_store(val, &ob4[i4]);
      }
    }
  }
}

extern "C" void kernel_launch(void* const* d_in, const int* in_sizes, int n_in,
                              void* d_out, int out_size, void* d_ws, size_t ws_size,
                              hipStream_t stream) {
  const float* q = (const float*)d_in[0];
  const float* k = (const float*)d_in[1];
  const float* v = (const float*)d_in[2];
  const int* mask_s = (const int*)d_in[3];
  const float* Wq_w = (const float*)d_in[5];
  const float* Wq_b = (const float*)d_in[6];
  const float* Wk_w = (const float*)d_in[7];
  const float* Wk_b = (const float*)d_in[8];
  const float* Wv_w = (const float*)d_in[9];
  const float* Wv_b = (const float*)d_in[10];
  const float* csw = (const float*)d_in[11];
  const float* csb = (const float*)d_in[12];
  float* out = (float*)d_out;

  float* ws = (float*)d_ws;
  float* sqb = ws;                            // 8
  float* skb = ws + 8;                        // 8 -> 16
  ushort* wvtf = (ushort*)(ws + 16);          // 131072 us -> ends f-idx 65552
  ushort* qwf = (ushort*)(ws + 65552);        // 4096 us -> 67600
  ushort* kwf = (ushort*)(ws + 67600);        // 4096 us -> 69648
  float* qsum = ws + 69648;                   // 1441792
  float* ksumraw = qsum + 1441792;            // 720896
  float* vs_inner = ksumraw + 720896;         // 1048576
  float* vtsum = vs_inner + 1048576;          // 1441792

  hipLaunchKernelGGL(prep_all_kernel, dim3(273), dim3(512), 0, stream,
                     Wq_w, Wq_b, Wk_w, Wk_b, Wv_w, qwf, kwf, wvtf, sqb, skb);
  hipLaunchKernelGGL(fused2_kernel, dim3(4160), dim3(512), 0, stream,
                     q, k, v, qwf, kwf, wvtf, sqb, skb, Wv_b,
                     qsum, ksumraw, vs_inner, vtsum);
  hipLaunchKernelGGL(final2_kernel, dim3(4096), dim3(512), 0, stream,
                     qsum, ksumraw, vs_inner, vtsum, mask_s, csw, csb, out);
}

// Round 15
// 205.669 us; speedup vs baseline: 1.5254x; 1.0483x over previous
//
#include <hip/hip_runtime.h>

// B=256, F=16, FO=32, J=22, H=8, IN=256, OUT=512, HID=64, HS=32
// Degenerate-einsum analysis:
//   attn_s = qsum (x) ksum  (outer product of channel sums)
//   x_s    = diag(softmax(attn_s)) * (sum_u v_s')
//   x_t    = sum_f v_t  (softmax sums to 1; q_t/k_t/conv_t/mask_t unused)
// Round 15: MEGA-KERNEL — block = (b,h) is fully self-contained:
//   qsum[b,h] <- q-slabs fo2 in [4h,4h+4) (88 rows); ksumraw[b,h] <- k-slab
//   fp=h (44 rows); vssum conv is local to vproj's own output. One block does
//   stage-v -> qk-direct tiles (LDS qs/kraw) -> v-MFMA+dump/gather (LDS) ->
//   convs -> softmax -> 176KB output write. Zero intermediates; read+write
//   streams overlap across 2048 staggered blocks. 2 launches total.

#define NEGV (-1000000000.0f)

typedef __attribute__((ext_vector_type(8))) short short8;
typedef __attribute__((ext_vector_type(4))) float f32x4;

__device__ inline ushort f2bf(float f) {
  union { float f; unsigned u; } a;
  a.f = f;
  unsigned u = a.u;
  return (ushort)((u + 0x7FFFu + ((u >> 16) & 1u)) >> 16);  // RNE
}

// stage 44 rows x 256 f32 -> bf16 into lA with granule swizzle gp = gl ^ (row&7)
#define PUTG(g, pa, pb)                                                        \
  {                                                                            \
    int row_ = (g) >> 5, gl_ = (g) & 31;                                       \
    int gp_ = gl_ ^ (row_ & 7);                                                \
    short8 u_;                                                                 \
    u_[0] = (short)f2bf(pa[0]); u_[1] = (short)f2bf(pa[1]);                    \
    u_[2] = (short)f2bf(pa[2]); u_[3] = (short)f2bf(pa[3]);                    \
    u_[4] = (short)f2bf(pb[0]); u_[5] = (short)f2bf(pb[1]);                    \
    u_[6] = (short)f2bf(pb[2]); u_[7] = (short)f2bf(pb[3]);                    \
    *reinterpret_cast<short8*>(&lA[row_ * 256 + gp_ * 8]) = u_;                \
  }

#define STAGE44_NT(SRCPTR)                                                     \
  {                                                                            \
    const float* vsrc_ = (SRCPTR);                                             \
    int g0 = tid, g1 = tid + 512, g2 = tid + 1024;                             \
    f32x4 a0 = __builtin_nontemporal_load(                                     \
        reinterpret_cast<const f32x4*>(vsrc_ + g0 * 8));                       \
    f32x4 b0 = __builtin_nontemporal_load(                                     \
        reinterpret_cast<const f32x4*>(vsrc_ + g0 * 8 + 4));                   \
    f32x4 a1 = __builtin_nontemporal_load(                                     \
        reinterpret_cast<const f32x4*>(vsrc_ + g1 * 8));                       \
    f32x4 b1 = __builtin_nontemporal_load(                                     \
        reinterpret_cast<const f32x4*>(vsrc_ + g1 * 8 + 4));                   \
    f32x4 a2 = {0, 0, 0, 0}, b2 = {0, 0, 0, 0};                                \
    if (g2 < 1408) {                                                           \
      a2 = __builtin_nontemporal_load(                                         \
          reinterpret_cast<const f32x4*>(vsrc_ + g2 * 8));                     \
      b2 = __builtin_nontemporal_load(                                         \
          reinterpret_cast<const f32x4*>(vsrc_ + g2 * 8 + 4));                 \
    }                                                                          \
    PUTG(g0, a0, b0);                                                          \
    PUTG(g1, a1, b1);                                                          \
    if (g2 < 1408) PUTG(g2, a2, b2);                                           \
    if (tid < 128) {                                                           \
      int g = 1408 + tid;                                                      \
      int row_ = g >> 5, gp_ = (g & 31) ^ (row_ & 7);                          \
      short8 z = {0, 0, 0, 0, 0, 0, 0, 0};                                     \
      *reinterpret_cast<short8*>(&lA[row_ * 256 + gp_ * 8]) = z;               \
    }                                                                          \
  }

// ---------------- prep_all: wvt (0..255) + qkwf (256..271) + prepb (272) ----
__global__ __launch_bounds__(512) void prep_all_kernel(const float* __restrict__ Wq_w,
                                                       const float* __restrict__ Wq_b,
                                                       const float* __restrict__ Wk_w,
                                                       const float* __restrict__ Wk_b,
                                                       const float* __restrict__ Wv_w,
                                                       ushort* __restrict__ qwf,
                                                       ushort* __restrict__ kwf,
                                                       ushort* __restrict__ wvtf,
                                                       float* __restrict__ sqb,
                                                       float* __restrict__ skb) {
  int bx = blockIdx.x, tid = threadIdx.x;
  if (bx < 256) {
    int idx = bx * 512 + tid;  // 0..131071
    int e = idx & 7;
    int lane = (idx >> 3) & 63;
    int ks = (idx >> 9) & 7;
    int nt = idx >> 12;
    int r0 = lane & 15, kb = lane >> 4;
    int k = ks * 32 + kb * 8 + e;
    int ch = nt * 16 + r0;
    wvtf[idx] = f2bf(Wv_w[k * 512 + ch]);
  } else if (bx < 272) {
    int idx = (bx - 256) * 512 + tid;  // 0..8191
    int which = idx >> 12;
    int r = idx & 4095;
    int e = r & 7;
    int lane = (r >> 3) & 63;
    int ks = r >> 9;
    int m = lane & 15, kb = lane >> 4;
    int k = ks * 32 + kb * 8 + e;
    float s = 0.f;
    if (m < 8) {
      const float* W = which ? Wk_w : Wq_w;
      const float4* p = reinterpret_cast<const float4*>(W + (size_t)k * 512 + m * 64);
      #pragma unroll
      for (int c4 = 0; c4 < 8; ++c4) {
        float4 x = p[c4];
        s += x.x + x.y + x.z + x.w;
      }
    }
    (which ? kwf : qwf)[r] = f2bf(s);
  } else {
    if (tid < 8) {
      float s = 0.f;
      for (int c = 0; c < 32; ++c) s += Wq_b[tid * 64 + c];
      sqb[tid] = s;
    } else if (tid < 16) {
      int mm = tid - 8;
      float s = 0.f;
      for (int c = 0; c < 32; ++c) s += Wk_b[mm * 64 + c];
      skb[mm] = s;
    }
  }
}

// ---------------- mega: everything for head-slice (b,h) in one block --------
__global__ __launch_bounds__(512, 2) void mega_kernel(const float* __restrict__ q,
                                                      const float* __restrict__ k,
                                                      const float* __restrict__ v,
                                                      const ushort* __restrict__ qwf,
                                                      const ushort* __restrict__ kwf,
                                                      const ushort* __restrict__ wvtf,
                                                      const float* __restrict__ sqb,
                                                      const float* __restrict__ skb,
                                                      const float* __restrict__ Wv_b,
                                                      const float* __restrict__ csw,
                                                      const float* __restrict__ csb,
                                                      const int* __restrict__ mask_s,
                                                      float* __restrict__ out) {
  int bh = blockIdx.x;  // b*8 + h
  int b = bh >> 3, h = bh & 7;
  __shared__ float sbuf[6656];     // lA (24.6KB ushort) / dump (26.6KB float)
  __shared__ float qs[32][23];     // qsum[t][s]
  __shared__ float kraw[16][23];   // ksumraw[floc][j]
  __shared__ float kss[32][23];    // ksum_s[t][j]
  __shared__ float vsg[16][33];    // vs_inner[f][d]
  __shared__ float vss[32][33];    // vssum[t][d]
  __shared__ float vtl[22][33];    // vtsum[j][g]
  __shared__ float dg[32][23];     // diag softmax
  __shared__ float lcsw[32][17];   // csw[t][f], csb in [16]
  __shared__ int msk[484];
  ushort* lA = reinterpret_cast<ushort*>(sbuf);
  float* dump = sbuf;
  int tid = threadIdx.x, lane = tid & 63, w = tid >> 6;
  int r0 = lane & 15, kb = lane >> 4;

  // ---- 1. v stage (nt loads in flight first) ----
  STAGE44_NT(v + (size_t)bh * 11264);

  // ---- 2. constants ----
  if (tid < 484) msk[tid] = mask_s[tid];
  {
    int t = tid >> 4, f = tid & 15;
    lcsw[t][f] = csw[t * 16 + f];
  }
  if (tid < 32) lcsw[tid][16] = csb[tid];

  // ---- 3. q/k direct tiles (no barrier; unique LDS scatter) ----
  // 9 units: u<6 -> q tile u (88 rows), u>=6 -> k tile u-6 (44 rows).
  // wave w does unit w; wave 0 also unit 8.
  const float* qbase = q + (size_t)(b * 704 + 4 * h * 22) * 256;
  const float* kbase = k + (size_t)(b * 352 + 2 * h * 22) * 256;
  for (int pass = 0; pass < 2; ++pass) {
    int u = pass == 0 ? w : 8;
    if (pass == 1 && w != 0) break;
    bool isK = u >= 6;
    int ut = isK ? u - 6 : u;
    int limit = isK ? 44 : 88;
    int rr = ut * 16 + r0;
    if (rr >= limit) rr = 0;  // clamp (results guarded on store)
    const float* src = (isK ? kbase : qbase) + (size_t)rr * 256;
    const ushort* wf = isK ? kwf : qwf;
    f32x4 acc = {0.f, 0.f, 0.f, 0.f};
    #pragma unroll
    for (int ks = 0; ks < 8; ++ks) {
      f32x4 xa = __builtin_nontemporal_load(
          reinterpret_cast<const f32x4*>(src + ks * 32 + kb * 8));
      f32x4 xb = __builtin_nontemporal_load(
          reinterpret_cast<const f32x4*>(src + ks * 32 + kb * 8 + 4));
      short8 a;
      a[0] = (short)f2bf(xa[0]); a[1] = (short)f2bf(xa[1]);
      a[2] = (short)f2bf(xa[2]); a[3] = (short)f2bf(xa[3]);
      a[4] = (short)f2bf(xb[0]); a[5] = (short)f2bf(xb[1]);
      a[6] = (short)f2bf(xb[2]); a[7] = (short)f2bf(xb[3]);
      short8 bf = *reinterpret_cast<const short8*>(wf + (ks * 64 + lane) * 8);
      acc = __builtin_amdgcn_mfma_f32_16x16x32_bf16(a, bf, acc, 0, 0, 0);
    }
    if (r0 < 8) {  // D: col = lane&15 = m, row = kb*4+reg (m89-verified)
      int m = r0;
      float bias = isK ? skb[m] : sqb[m];
      #pragma unroll
      for (int reg = 0; reg < 4; ++reg) {
        int R = ut * 16 + kb * 4 + reg;  // local row
        if (R < limit) {
          if (!isK) {
            int fo2l = R / 22, j2 = R % 22;   // fo2l == fo2&3 (fo2 = 4h+fo2l)
            int lf = fo2l * 11264 + j2 * 512 + m * 64;
            int t = lf / 1408;
            int s = (lf % 1408) >> 6;
            qs[t][s] = acc[reg] + bias;
          } else {
            int f2l = R / 22, j2 = R % 22;    // f2l == f2&1 (f2 = 2h+f2l)
            int lf = f2l * 11264 + j2 * 512 + m * 64;
            int floc = lf / 1408;
            int jj = (lf % 1408) >> 6;
            kraw[floc][jj] = acc[reg] + bias;
          }
        }
      }
    }
  }
  __syncthreads();  // lA staged + qs/kraw complete

  // ---- 4. v MFMA (R10-verified body) ----
  int nt0 = w * 4;
  f32x4 acc[3][4];
  #pragma unroll
  for (int m = 0; m < 3; ++m)
    #pragma unroll
    for (int n = 0; n < 4; ++n) acc[m][n] = (f32x4){0.f, 0.f, 0.f, 0.f};

  #pragma unroll
  for (int ks = 0; ks < 8; ++ks) {
    int go = ((ks * 4 + kb) ^ (r0 & 7)) * 8;
    short8 a0 = *reinterpret_cast<const short8*>(&lA[(r0) * 256 + go]);
    short8 a1 = *reinterpret_cast<const short8*>(&lA[(16 + r0) * 256 + go]);
    short8 a2 = *reinterpret_cast<const short8*>(&lA[(32 + r0) * 256 + go]);
    #pragma unroll
    for (int n = 0; n < 4; ++n) {
      short8 bf = *reinterpret_cast<const short8*>(
          wvtf + ((size_t)((nt0 + n) * 8 + ks) * 64 + lane) * 8);
      acc[0][n] = __builtin_amdgcn_mfma_f32_16x16x32_bf16(bf, a0, acc[0][n], 0, 0, 0);
      acc[1][n] = __builtin_amdgcn_mfma_f32_16x16x32_bf16(bf, a1, acc[1][n], 0, 0, 0);
      acc[2][n] = __builtin_amdgcn_mfma_f32_16x16x32_bf16(bf, a2, acc[2][n], 0, 0, 0);
    }
  }
  __syncthreads();  // lA reads done; sbuf becomes dump

  // ---- 5. dump/gather 4 phases -> vsg / vtl (LDS) ----
  #pragma unroll
  for (int n = 0; n < 4; ++n) {
    float4 bq = *reinterpret_cast<const float4*>(Wv_b + w * 64 + n * 16 + kb * 4);
    int dbase = tid * 13;
    #pragma unroll
    for (int m = 0; m < 3; ++m) {
      dump[dbase + m * 4 + 0] = acc[m][n][0] + bq.x;
      dump[dbase + m * 4 + 1] = acc[m][n][1] + bq.y;
      dump[dbase + m * 4 + 2] = acc[m][n][2] + bq.z;
      dump[dbase + m * 4 + 3] = acc[m][n][3] + bq.w;
    }
    __syncthreads();
    if (n < 2) {
      if (tid < 256) {
        int f = tid >> 4, rest = tid & 15;
        int kb2 = rest >> 2, reg = rest & 3;
        float s = 0.f;
        #pragma unroll
        for (int u = 0; u < 22; ++u) {
          int fj = f * 22 + u;
          int f2 = (fj >= 176) ? 1 : 0;
          int rem = fj - f2 * 176;
          int j = rem >> 3, ww = rem & 7;
          int vrow = f2 * 22 + j;
          int m = vrow >> 4, rr2 = vrow & 15;
          s += dump[(ww * 64 + kb2 * 16 + rr2) * 13 + m * 4 + reg];
        }
        vsg[f][n * 16 + kb2 * 4 + reg] = s;
      }
    } else {
      if (tid < 352) {
        int jj = tid >> 4, rest = tid & 15;
        int kb2 = rest >> 2, reg = rest & 3;
        float s = 0.f;
        #pragma unroll
        for (int f = 0; f < 16; ++f) {
          int fj = f * 22 + jj;
          int f2 = (fj >= 176) ? 1 : 0;
          int rem = fj - f2 * 176;
          int j = rem >> 3, ww = rem & 7;
          int vrow = f2 * 22 + j;
          int m = vrow >> 4, rr2 = vrow & 15;
          s += dump[(ww * 64 + kb2 * 16 + rr2) * 13 + m * 4 + reg];
        }
        vtl[jj][(n - 2) * 16 + kb2 * 4 + reg] = s;
      }
    }
    __syncthreads();
  }

  // ---- 6. convs: kss (704) and vss (1024) ----
  for (int o = tid; o < 704; o += 512) {
    int t = o / 22, j = o % 22;
    float a = 32.0f * lcsw[t][16];
    #pragma unroll
    for (int f = 0; f < 16; ++f) a += lcsw[t][f] * kraw[f][j];
    kss[t][j] = a;
  }
  {
    int t = tid >> 4, d2 = (tid & 15) * 2;
    float a0 = 22.0f * lcsw[t][16], a1 = a0;
    #pragma unroll
    for (int f = 0; f < 16; ++f) {
      float cw = lcsw[t][f];
      a0 += cw * vsg[f][d2];
      a1 += cw * vsg[f][d2 + 1];
    }
    vss[t][d2] = a0;
    vss[t][d2 + 1] = a1;
  }
  __syncthreads();

  // ---- 7. diag softmax (704) ----
  for (int p = tid; p < 704; p += 512) {
    int t = p / 22, s = p % 22;
    float qv = qs[t][s];
    float mx = -3.0e38f;
    #pragma unroll
    for (int u = 0; u < 22; ++u) {
      float av = msk[s * 22 + u] ? qv * kss[t][u] : NEGV;
      mx = fmaxf(mx, av);
    }
    float den = 0.f;
    #pragma unroll
    for (int u = 0; u < 22; ++u) {
      float av = msk[s * 22 + u] ? qv * kss[t][u] : NEGV;
      den += expf(av - mx);
    }
    float as = msk[s * 22 + s] ? qv * kss[t][s] : NEGV;
    dg[t][s] = expf(as - mx) / den;
  }
  __syncthreads();

  // ---- 8. output write: out[b, t, s, h*64 + d], 11264 float4 ----
  float* ob = out + (size_t)b * 32 * 22 * 512 + h * 64;
  for (int i = tid; i < 11264; i += 512) {
    int ts = i >> 4, w4 = i & 15;
    int t = ts / 22, s = ts % 22;
    int d0 = w4 * 4;
    f32x4 val;
    if (d0 < 32) {
      float g = dg[t][s];
      const float* vp = &vss[t][d0];
      val[0] = g * vp[0]; val[1] = g * vp[1]; val[2] = g * vp[2]; val[3] = g * vp[3];
    } else {
      const float* tp = &vtl[s][d0 - 32];
      val[0] = tp[0]; val[1] = tp[1]; val[2] = tp[2]; val[3] = tp[3];
    }
    __builtin_nontemporal_store(
        val, reinterpret_cast<f32x4*>(ob + (size_t)(t * 22 + s) * 512 + d0));
  }
}

extern "C" void kernel_launch(void* const* d_in, const int* in_sizes, int n_in,
                              void* d_out, int out_size, void* d_ws, size_t ws_size,
                              hipStream_t stream) {
  const float* q = (const float*)d_in[0];
  const float* k = (const float*)d_in[1];
  const float* v = (const float*)d_in[2];
  const int* mask_s = (const int*)d_in[3];
  const float* Wq_w = (const float*)d_in[5];
  const float* Wq_b = (const float*)d_in[6];
  const float* Wk_w = (const float*)d_in[7];
  const float* Wk_b = (const float*)d_in[8];
  const float* Wv_w = (const float*)d_in[9];
  const float* Wv_b = (const float*)d_in[10];
  const float* csw = (const float*)d_in[11];
  const float* csb = (const float*)d_in[12];
  float* out = (float*)d_out;

  float* ws = (float*)d_ws;
  float* sqb = ws;                            // 8
  float* skb = ws + 8;                        // 8 -> 16
  ushort* wvtf = (ushort*)(ws + 16);          // 131072 us -> ends f-idx 65552
  ushort* qwf = (ushort*)(ws + 65552);        // 4096 us -> 67600
  ushort* kwf = (ushort*)(ws + 67600);        // 4096 us -> 69648

  hipLaunchKernelGGL(prep_all_kernel, dim3(273), dim3(512), 0, stream,
                     Wq_w, Wq_b, Wk_w, Wk_b, Wv_w, qwf, kwf, wvtf, sqb, skb);
  hipLaunchKernelGGL(mega_kernel, dim3(2048), dim3(512), 0, stream,
                     q, k, v, qwf, kwf, wvtf, sqb, skb, Wv_b, csw, csb, mask_s, out);
}

// Round 16
// 205.526 us; speedup vs baseline: 1.5265x; 1.0007x over previous
//
#include <hip/hip_runtime.h>

// B=256, F=16, FO=32, J=22, H=8, IN=256, OUT=512, HID=64, HS=32
// Degenerate-einsum analysis:
//   attn_s = qsum (x) ksum  (outer product of channel sums)
//   x_s    = diag(softmax(attn_s)) * (sum_u v_s')
//   x_t    = sum_f v_t  (softmax sums to 1; q_t/k_t/conv_t/mask_t unused)
// Round 16: R15 mega-kernel + LDS overlay — kss/vss/dg (10.1KB) fold into
// sbuf (dead after the gather phases) -> block LDS 50.3KB -> 40.2KB ->
// 4 blocks/CU (was 2). More staggered load/write streams per CU -> higher
// HBM duty cycle. All verified bodies byte-identical.

#define NEGV (-1000000000.0f)

typedef __attribute__((ext_vector_type(8))) short short8;
typedef __attribute__((ext_vector_type(4))) float f32x4;

__device__ inline ushort f2bf(float f) {
  union { float f; unsigned u; } a;
  a.f = f;
  unsigned u = a.u;
  return (ushort)((u + 0x7FFFu + ((u >> 16) & 1u)) >> 16);  // RNE
}

// stage 44 rows x 256 f32 -> bf16 into lA with granule swizzle gp = gl ^ (row&7)
#define PUTG(g, pa, pb)                                                        \
  {                                                                            \
    int row_ = (g) >> 5, gl_ = (g) & 31;                                       \
    int gp_ = gl_ ^ (row_ & 7);                                                \
    short8 u_;                                                                 \
    u_[0] = (short)f2bf(pa[0]); u_[1] = (short)f2bf(pa[1]);                    \
    u_[2] = (short)f2bf(pa[2]); u_[3] = (short)f2bf(pa[3]);                    \
    u_[4] = (short)f2bf(pb[0]); u_[5] = (short)f2bf(pb[1]);                    \
    u_[6] = (short)f2bf(pb[2]); u_[7] = (short)f2bf(pb[3]);                    \
    *reinterpret_cast<short8*>(&lA[row_ * 256 + gp_ * 8]) = u_;                \
  }

#define STAGE44_NT(SRCPTR)                                                     \
  {                                                                            \
    const float* vsrc_ = (SRCPTR);                                             \
    int g0 = tid, g1 = tid + 512, g2 = tid + 1024;                             \
    f32x4 a0 = __builtin_nontemporal_load(                                     \
        reinterpret_cast<const f32x4*>(vsrc_ + g0 * 8));                       \
    f32x4 b0 = __builtin_nontemporal_load(                                     \
        reinterpret_cast<const f32x4*>(vsrc_ + g0 * 8 + 4));                   \
    f32x4 a1 = __builtin_nontemporal_load(                                     \
        reinterpret_cast<const f32x4*>(vsrc_ + g1 * 8));                       \
    f32x4 b1 = __builtin_nontemporal_load(                                     \
        reinterpret_cast<const f32x4*>(vsrc_ + g1 * 8 + 4));                   \
    f32x4 a2 = {0, 0, 0, 0}, b2 = {0, 0, 0, 0};                                \
    if (g2 < 1408) {                                                           \
      a2 = __builtin_nontemporal_load(                                         \
          reinterpret_cast<const f32x4*>(vsrc_ + g2 * 8));                     \
      b2 = __builtin_nontemporal_load(                                         \
          reinterpret_cast<const f32x4*>(vsrc_ + g2 * 8 + 4));                 \
    }                                                                          \
    PUTG(g0, a0, b0);                                                          \
    PUTG(g1, a1, b1);                                                          \
    if (g2 < 1408) PUTG(g2, a2, b2);                                           \
    if (tid < 128) {                                                           \
      int g = 1408 + tid;                                                      \
      int row_ = g >> 5, gp_ = (g & 31) ^ (row_ & 7);                          \
      short8 z = {0, 0, 0, 0, 0, 0, 0, 0};                                     \
      *reinterpret_cast<short8*>(&lA[row_ * 256 + gp_ * 8]) = z;               \
    }                                                                          \
  }

// ---------------- prep_all: wvt (0..255) + qkwf (256..271) + prepb (272) ----
__global__ __launch_bounds__(512) void prep_all_kernel(const float* __restrict__ Wq_w,
                                                       const float* __restrict__ Wq_b,
                                                       const float* __restrict__ Wk_w,
                                                       const float* __restrict__ Wk_b,
                                                       const float* __restrict__ Wv_w,
                                                       ushort* __restrict__ qwf,
                                                       ushort* __restrict__ kwf,
                                                       ushort* __restrict__ wvtf,
                                                       float* __restrict__ sqb,
                                                       float* __restrict__ skb) {
  int bx = blockIdx.x, tid = threadIdx.x;
  if (bx < 256) {
    int idx = bx * 512 + tid;  // 0..131071
    int e = idx & 7;
    int lane = (idx >> 3) & 63;
    int ks = (idx >> 9) & 7;
    int nt = idx >> 12;
    int r0 = lane & 15, kb = lane >> 4;
    int k = ks * 32 + kb * 8 + e;
    int ch = nt * 16 + r0;
    wvtf[idx] = f2bf(Wv_w[k * 512 + ch]);
  } else if (bx < 272) {
    int idx = (bx - 256) * 512 + tid;  // 0..8191
    int which = idx >> 12;
    int r = idx & 4095;
    int e = r & 7;
    int lane = (r >> 3) & 63;
    int ks = r >> 9;
    int m = lane & 15, kb = lane >> 4;
    int k = ks * 32 + kb * 8 + e;
    float s = 0.f;
    if (m < 8) {
      const float* W = which ? Wk_w : Wq_w;
      const float4* p = reinterpret_cast<const float4*>(W + (size_t)k * 512 + m * 64);
      #pragma unroll
      for (int c4 = 0; c4 < 8; ++c4) {
        float4 x = p[c4];
        s += x.x + x.y + x.z + x.w;
      }
    }
    (which ? kwf : qwf)[r] = f2bf(s);
  } else {
    if (tid < 8) {
      float s = 0.f;
      for (int c = 0; c < 32; ++c) s += Wq_b[tid * 64 + c];
      sqb[tid] = s;
    } else if (tid < 16) {
      int mm = tid - 8;
      float s = 0.f;
      for (int c = 0; c < 32; ++c) s += Wk_b[mm * 64 + c];
      skb[mm] = s;
    }
  }
}

// ---------------- mega: everything for head-slice (b,h) in one block --------
__global__ __launch_bounds__(512, 2) void mega_kernel(const float* __restrict__ q,
                                                      const float* __restrict__ k,
                                                      const float* __restrict__ v,
                                                      const ushort* __restrict__ qwf,
                                                      const ushort* __restrict__ kwf,
                                                      const ushort* __restrict__ wvtf,
                                                      const float* __restrict__ sqb,
                                                      const float* __restrict__ skb,
                                                      const float* __restrict__ Wv_b,
                                                      const float* __restrict__ csw,
                                                      const float* __restrict__ csb,
                                                      const int* __restrict__ mask_s,
                                                      float* __restrict__ out) {
  int bh = blockIdx.x;  // b*8 + h
  int b = bh >> 3, h = bh & 7;
  __shared__ float sbuf[6656];     // lA (24.6KB) / dump (26.6KB) / kss+vss+dg
  __shared__ float qs[32][23];     // qsum[t][s]
  __shared__ float kraw[16][23];   // ksumraw[floc][j]
  __shared__ float vsg[16][33];    // vs_inner[f][d]
  __shared__ float vtl[22][33];    // vtsum[j][g]
  __shared__ float lcsw[32][17];   // csw[t][f], csb in [16]
  __shared__ int msk[484];
  ushort* lA = reinterpret_cast<ushort*>(sbuf);
  float* dump = sbuf;
  // overlay (live only after gather phases; sbuf dead then):
  float* kssp = sbuf;              // [32][23] -> 736
  float* vssp = sbuf + 736;        // [32][33] -> 1056
  float* dgp = sbuf + 1792;        // [32][23] -> 736   (total 2528 <= 6656)
  int tid = threadIdx.x, lane = tid & 63, w = tid >> 6;
  int r0 = lane & 15, kb = lane >> 4;

  // ---- 1. v stage (nt loads in flight first) ----
  STAGE44_NT(v + (size_t)bh * 11264);

  // ---- 2. constants ----
  if (tid < 484) msk[tid] = mask_s[tid];
  {
    int t = tid >> 4, f = tid & 15;
    lcsw[t][f] = csw[t * 16 + f];
  }
  if (tid < 32) lcsw[tid][16] = csb[tid];

  // ---- 3. q/k direct tiles (no barrier; unique LDS scatter) ----
  const float* qbase = q + (size_t)(b * 704 + 4 * h * 22) * 256;
  const float* kbase = k + (size_t)(b * 352 + 2 * h * 22) * 256;
  for (int pass = 0; pass < 2; ++pass) {
    int u = pass == 0 ? w : 8;
    if (pass == 1 && w != 0) break;
    bool isK = u >= 6;
    int ut = isK ? u - 6 : u;
    int limit = isK ? 44 : 88;
    int rr = ut * 16 + r0;
    if (rr >= limit) rr = 0;  // clamp (results guarded on store)
    const float* src = (isK ? kbase : qbase) + (size_t)rr * 256;
    const ushort* wf = isK ? kwf : qwf;
    f32x4 acc = {0.f, 0.f, 0.f, 0.f};
    #pragma unroll
    for (int ks = 0; ks < 8; ++ks) {
      f32x4 xa = __builtin_nontemporal_load(
          reinterpret_cast<const f32x4*>(src + ks * 32 + kb * 8));
      f32x4 xb = __builtin_nontemporal_load(
          reinterpret_cast<const f32x4*>(src + ks * 32 + kb * 8 + 4));
      short8 a;
      a[0] = (short)f2bf(xa[0]); a[1] = (short)f2bf(xa[1]);
      a[2] = (short)f2bf(xa[2]); a[3] = (short)f2bf(xa[3]);
      a[4] = (short)f2bf(xb[0]); a[5] = (short)f2bf(xb[1]);
      a[6] = (short)f2bf(xb[2]); a[7] = (short)f2bf(xb[3]);
      short8 bf = *reinterpret_cast<const short8*>(wf + (ks * 64 + lane) * 8);
      acc = __builtin_amdgcn_mfma_f32_16x16x32_bf16(a, bf, acc, 0, 0, 0);
    }
    if (r0 < 8) {  // D: col = lane&15 = m, row = kb*4+reg (m89-verified)
      int m = r0;
      float bias = isK ? skb[m] : sqb[m];
      #pragma unroll
      for (int reg = 0; reg < 4; ++reg) {
        int R = ut * 16 + kb * 4 + reg;  // local row
        if (R < limit) {
          if (!isK) {
            int fo2l = R / 22, j2 = R % 22;
            int lf = fo2l * 11264 + j2 * 512 + m * 64;
            int t = lf / 1408;
            int s = (lf % 1408) >> 6;
            qs[t][s] = acc[reg] + bias;
          } else {
            int f2l = R / 22, j2 = R % 22;
            int lf = f2l * 11264 + j2 * 512 + m * 64;
            int floc = lf / 1408;
            int jj = (lf % 1408) >> 6;
            kraw[floc][jj] = acc[reg] + bias;
          }
        }
      }
    }
  }
  __syncthreads();  // lA staged + qs/kraw complete

  // ---- 4. v MFMA (R10-verified body) ----
  int nt0 = w * 4;
  f32x4 acc[3][4];
  #pragma unroll
  for (int m = 0; m < 3; ++m)
    #pragma unroll
    for (int n = 0; n < 4; ++n) acc[m][n] = (f32x4){0.f, 0.f, 0.f, 0.f};

  #pragma unroll
  for (int ks = 0; ks < 8; ++ks) {
    int go = ((ks * 4 + kb) ^ (r0 & 7)) * 8;
    short8 a0 = *reinterpret_cast<const short8*>(&lA[(r0) * 256 + go]);
    short8 a1 = *reinterpret_cast<const short8*>(&lA[(16 + r0) * 256 + go]);
    short8 a2 = *reinterpret_cast<const short8*>(&lA[(32 + r0) * 256 + go]);
    #pragma unroll
    for (int n = 0; n < 4; ++n) {
      short8 bf = *reinterpret_cast<const short8*>(
          wvtf + ((size_t)((nt0 + n) * 8 + ks) * 64 + lane) * 8);
      acc[0][n] = __builtin_amdgcn_mfma_f32_16x16x32_bf16(bf, a0, acc[0][n], 0, 0, 0);
      acc[1][n] = __builtin_amdgcn_mfma_f32_16x16x32_bf16(bf, a1, acc[1][n], 0, 0, 0);
      acc[2][n] = __builtin_amdgcn_mfma_f32_16x16x32_bf16(bf, a2, acc[2][n], 0, 0, 0);
    }
  }
  __syncthreads();  // lA reads done; sbuf becomes dump

  // ---- 5. dump/gather 4 phases -> vsg / vtl (LDS) ----
  #pragma unroll
  for (int n = 0; n < 4; ++n) {
    float4 bq = *reinterpret_cast<const float4*>(Wv_b + w * 64 + n * 16 + kb * 4);
    int dbase = tid * 13;
    #pragma unroll
    for (int m = 0; m < 3; ++m) {
      dump[dbase + m * 4 + 0] = acc[m][n][0] + bq.x;
      dump[dbase + m * 4 + 1] = acc[m][n][1] + bq.y;
      dump[dbase + m * 4 + 2] = acc[m][n][2] + bq.z;
      dump[dbase + m * 4 + 3] = acc[m][n][3] + bq.w;
    }
    __syncthreads();
    if (n < 2) {
      if (tid < 256) {
        int f = tid >> 4, rest = tid & 15;
        int kb2 = rest >> 2, reg = rest & 3;
        float s = 0.f;
        #pragma unroll
        for (int u = 0; u < 22; ++u) {
          int fj = f * 22 + u;
          int f2 = (fj >= 176) ? 1 : 0;
          int rem = fj - f2 * 176;
          int j = rem >> 3, ww = rem & 7;
          int vrow = f2 * 22 + j;
          int m = vrow >> 4, rr2 = vrow & 15;
          s += dump[(ww * 64 + kb2 * 16 + rr2) * 13 + m * 4 + reg];
        }
        vsg[f][n * 16 + kb2 * 4 + reg] = s;
      }
    } else {
      if (tid < 352) {
        int jj = tid >> 4, rest = tid & 15;
        int kb2 = rest >> 2, reg = rest & 3;
        float s = 0.f;
        #pragma unroll
        for (int f = 0; f < 16; ++f) {
          int fj = f * 22 + jj;
          int f2 = (fj >= 176) ? 1 : 0;
          int rem = fj - f2 * 176;
          int j = rem >> 3, ww = rem & 7;
          int vrow = f2 * 22 + j;
          int m = vrow >> 4, rr2 = vrow & 15;
          s += dump[(ww * 64 + kb2 * 16 + rr2) * 13 + m * 4 + reg];
        }
        vtl[jj][(n - 2) * 16 + kb2 * 4 + reg] = s;
      }
    }
    __syncthreads();
  }

  // ---- 6. convs: kss (704) and vss (1024) — into sbuf overlay ----
  for (int o = tid; o < 704; o += 512) {
    int t = o / 22, j = o % 22;
    float a = 32.0f * lcsw[t][16];
    #pragma unroll
    for (int f = 0; f < 16; ++f) a += lcsw[t][f] * kraw[f][j];
    kssp[t * 23 + j] = a;
  }
  {
    int t = tid >> 4, d2 = (tid & 15) * 2;
    float a0 = 22.0f * lcsw[t][16], a1 = a0;
    #pragma unroll
    for (int f = 0; f < 16; ++f) {
      float cw = lcsw[t][f];
      a0 += cw * vsg[f][d2];
      a1 += cw * vsg[f][d2 + 1];
    }
    vssp[t * 33 + d2] = a0;
    vssp[t * 33 + d2 + 1] = a1;
  }
  __syncthreads();

  // ---- 7. diag softmax (704) ----
  for (int p = tid; p < 704; p += 512) {
    int t = p / 22, s = p % 22;
    float qv = qs[t][s];
    float mx = -3.0e38f;
    #pragma unroll
    for (int u = 0; u < 22; ++u) {
      float av = msk[s * 22 + u] ? qv * kssp[t * 23 + u] : NEGV;
      mx = fmaxf(mx, av);
    }
    float den = 0.f;
    #pragma unroll
    for (int u = 0; u < 22; ++u) {
      float av = msk[s * 22 + u] ? qv * kssp[t * 23 + u] : NEGV;
      den += expf(av - mx);
    }
    float as = msk[s * 22 + s] ? qv * kssp[t * 23 + s] : NEGV;
    dgp[t * 23 + s] = expf(as - mx) / den;
  }
  __syncthreads();

  // ---- 8. output write: out[b, t, s, h*64 + d], 11264 float4 ----
  float* ob = out + (size_t)b * 32 * 22 * 512 + h * 64;
  for (int i = tid; i < 11264; i += 512) {
    int ts = i >> 4, w4 = i & 15;
    int t = ts / 22, s = ts % 22;
    int d0 = w4 * 4;
    f32x4 val;
    if (d0 < 32) {
      float g = dgp[t * 23 + s];
      const float* vp = &vssp[t * 33 + d0];
      val[0] = g * vp[0]; val[1] = g * vp[1]; val[2] = g * vp[2]; val[3] = g * vp[3];
    } else {
      const float* tp = &vtl[s][d0 - 32];
      val[0] = tp[0]; val[1] = tp[1]; val[2] = tp[2]; val[3] = tp[3];
    }
    __builtin_nontemporal_store(
        val, reinterpret_cast<f32x4*>(ob + (size_t)(t * 22 + s) * 512 + d0));
  }
}

extern "C" void kernel_launch(void* const* d_in, const int* in_sizes, int n_in,
                              void* d_out, int out_size, void* d_ws, size_t ws_size,
                              hipStream_t stream) {
  const float* q = (const float*)d_in[0];
  const float* k = (const float*)d_in[1];
  const float* v = (const float*)d_in[2];
  const int* mask_s = (const int*)d_in[3];
  const float* Wq_w = (const float*)d_in[5];
  const float* Wq_b = (const float*)d_in[6];
  const float* Wk_w = (const float*)d_in[7];
  const float* Wk_b = (const float*)d_in[8];
  const float* Wv_w = (const float*)d_in[9];
  const float* Wv_b = (const float*)d_in[10];
  const float* csw = (const float*)d_in[11];
  const float* csb = (const float*)d_in[12];
  float* out = (float*)d_out;

  float* ws = (float*)d_ws;
  float* sqb = ws;                            // 8
  float* skb = ws + 8;                        // 8 -> 16
  ushort* wvtf = (ushort*)(ws + 16);          // 131072 us -> ends f-idx 65552
  ushort* qwf = (ushort*)(ws + 65552);        // 4096 us -> 67600
  ushort* kwf = (ushort*)(ws + 67600);        // 4096 us -> 69648

  hipLaunchKernelGGL(prep_all_kernel, dim3(273), dim3(512), 0, stream,
                     Wq_w, Wq_b, Wk_w, Wk_b, Wv_w, qwf, kwf, wvtf, sqb, skb);
  hipLaunchKernelGGL(mega_kernel, dim3(2048), dim3(512), 0, stream,
                     q, k, v, qwf, kwf, wvtf, sqb, skb, Wv_b, csw, csb, mask_s, out);
}

// Round 17
// 187.863 us; speedup vs baseline: 1.6700x; 1.0940x over previous
//
#include <hip/hip_runtime.h>

// B=256, F=16, FO=32, J=22, H=8, IN=256, OUT=512, HID=64, HS=32
// Degenerate-einsum analysis:
//   attn_s = qsum (x) ksum  (outer product of channel sums)
//   x_s    = diag(softmax(attn_s)) * (sum_u v_s')
//   x_t    = sum_f v_t  (softmax sums to 1; q_t/k_t/conv_t/mask_t unused)
// Round 17 (A/B on R16's 205.5us): write-only profile pass showed output
// draining at 1.65 TB/s. (1) remove nontemporal from output stores (added
// un-A/B'd in R13; bypasses L2 write combining); (2) vt-half of output
// (t-independent) written right after gather, overlapping convs/softmax.

#define NEGV (-1000000000.0f)

typedef __attribute__((ext_vector_type(8))) short short8;
typedef __attribute__((ext_vector_type(4))) float f32x4;

__device__ inline ushort f2bf(float f) {
  union { float f; unsigned u; } a;
  a.f = f;
  unsigned u = a.u;
  return (ushort)((u + 0x7FFFu + ((u >> 16) & 1u)) >> 16);  // RNE
}

// stage 44 rows x 256 f32 -> bf16 into lA with granule swizzle gp = gl ^ (row&7)
#define PUTG(g, pa, pb)                                                        \
  {                                                                            \
    int row_ = (g) >> 5, gl_ = (g) & 31;                                       \
    int gp_ = gl_ ^ (row_ & 7);                                                \
    short8 u_;                                                                 \
    u_[0] = (short)f2bf(pa[0]); u_[1] = (short)f2bf(pa[1]);                    \
    u_[2] = (short)f2bf(pa[2]); u_[3] = (short)f2bf(pa[3]);                    \
    u_[4] = (short)f2bf(pb[0]); u_[5] = (short)f2bf(pb[1]);                    \
    u_[6] = (short)f2bf(pb[2]); u_[7] = (short)f2bf(pb[3]);                    \
    *reinterpret_cast<short8*>(&lA[row_ * 256 + gp_ * 8]) = u_;                \
  }

#define STAGE44_NT(SRCPTR)                                                     \
  {                                                                            \
    const float* vsrc_ = (SRCPTR);                                             \
    int g0 = tid, g1 = tid + 512, g2 = tid + 1024;                             \
    f32x4 a0 = __builtin_nontemporal_load(                                     \
        reinterpret_cast<const f32x4*>(vsrc_ + g0 * 8));                       \
    f32x4 b0 = __builtin_nontemporal_load(                                     \
        reinterpret_cast<const f32x4*>(vsrc_ + g0 * 8 + 4));                   \
    f32x4 a1 = __builtin_nontemporal_load(                                     \
        reinterpret_cast<const f32x4*>(vsrc_ + g1 * 8));                       \
    f32x4 b1 = __builtin_nontemporal_load(                                     \
        reinterpret_cast<const f32x4*>(vsrc_ + g1 * 8 + 4));                   \
    f32x4 a2 = {0, 0, 0, 0}, b2 = {0, 0, 0, 0};                                \
    if (g2 < 1408) {                                                           \
      a2 = __builtin_nontemporal_load(                                         \
          reinterpret_cast<const f32x4*>(vsrc_ + g2 * 8));                     \
      b2 = __builtin_nontemporal_load(                                         \
          reinterpret_cast<const f32x4*>(vsrc_ + g2 * 8 + 4));                 \
    }                                                                          \
    PUTG(g0, a0, b0);                                                          \
    PUTG(g1, a1, b1);                                                          \
    if (g2 < 1408) PUTG(g2, a2, b2);                                           \
    if (tid < 128) {                                                           \
      int g = 1408 + tid;                                                      \
      int row_ = g >> 5, gp_ = (g & 31) ^ (row_ & 7);                          \
      short8 z = {0, 0, 0, 0, 0, 0, 0, 0};                                     \
      *reinterpret_cast<short8*>(&lA[row_ * 256 + gp_ * 8]) = z;               \
    }                                                                          \
  }

// ---------------- prep_all: wvt (0..255) + qkwf (256..271) + prepb (272) ----
__global__ __launch_bounds__(512) void prep_all_kernel(const float* __restrict__ Wq_w,
                                                       const float* __restrict__ Wq_b,
                                                       const float* __restrict__ Wk_w,
                                                       const float* __restrict__ Wk_b,
                                                       const float* __restrict__ Wv_w,
                                                       ushort* __restrict__ qwf,
                                                       ushort* __restrict__ kwf,
                                                       ushort* __restrict__ wvtf,
                                                       float* __restrict__ sqb,
                                                       float* __restrict__ skb) {
  int bx = blockIdx.x, tid = threadIdx.x;
  if (bx < 256) {
    int idx = bx * 512 + tid;  // 0..131071
    int e = idx & 7;
    int lane = (idx >> 3) & 63;
    int ks = (idx >> 9) & 7;
    int nt = idx >> 12;
    int r0 = lane & 15, kb = lane >> 4;
    int k = ks * 32 + kb * 8 + e;
    int ch = nt * 16 + r0;
    wvtf[idx] = f2bf(Wv_w[k * 512 + ch]);
  } else if (bx < 272) {
    int idx = (bx - 256) * 512 + tid;  // 0..8191
    int which = idx >> 12;
    int r = idx & 4095;
    int e = r & 7;
    int lane = (r >> 3) & 63;
    int ks = r >> 9;
    int m = lane & 15, kb = lane >> 4;
    int k = ks * 32 + kb * 8 + e;
    float s = 0.f;
    if (m < 8) {
      const float* W = which ? Wk_w : Wq_w;
      const float4* p = reinterpret_cast<const float4*>(W + (size_t)k * 512 + m * 64);
      #pragma unroll
      for (int c4 = 0; c4 < 8; ++c4) {
        float4 x = p[c4];
        s += x.x + x.y + x.z + x.w;
      }
    }
    (which ? kwf : qwf)[r] = f2bf(s);
  } else {
    if (tid < 8) {
      float s = 0.f;
      for (int c = 0; c < 32; ++c) s += Wq_b[tid * 64 + c];
      sqb[tid] = s;
    } else if (tid < 16) {
      int mm = tid - 8;
      float s = 0.f;
      for (int c = 0; c < 32; ++c) s += Wk_b[mm * 64 + c];
      skb[mm] = s;
    }
  }
}

// ---------------- mega: everything for head-slice (b,h) in one block --------
__global__ __launch_bounds__(512, 2) void mega_kernel(const float* __restrict__ q,
                                                      const float* __restrict__ k,
                                                      const float* __restrict__ v,
                                                      const ushort* __restrict__ qwf,
                                                      const ushort* __restrict__ kwf,
                                                      const ushort* __restrict__ wvtf,
                                                      const float* __restrict__ sqb,
                                                      const float* __restrict__ skb,
                                                      const float* __restrict__ Wv_b,
                                                      const float* __restrict__ csw,
                                                      const float* __restrict__ csb,
                                                      const int* __restrict__ mask_s,
                                                      float* __restrict__ out) {
  int bh = blockIdx.x;  // b*8 + h
  int b = bh >> 3, h = bh & 7;
  __shared__ float sbuf[6656];     // lA (24.6KB) / dump (26.6KB) / kss+vss+dg
  __shared__ float qs[32][23];     // qsum[t][s]
  __shared__ float kraw[16][23];   // ksumraw[floc][j]
  __shared__ float vsg[16][33];    // vs_inner[f][d]
  __shared__ float vtl[22][33];    // vtsum[j][g]
  __shared__ float lcsw[32][17];   // csw[t][f], csb in [16]
  __shared__ int msk[484];
  ushort* lA = reinterpret_cast<ushort*>(sbuf);
  float* dump = sbuf;
  // overlay (live only after gather phases; sbuf dead then):
  float* kssp = sbuf;              // [32][23] -> 736
  float* vssp = sbuf + 736;        // [32][33] -> 1056
  float* dgp = sbuf + 1792;        // [32][23] -> 736   (total 2528 <= 6656)
  int tid = threadIdx.x, lane = tid & 63, w = tid >> 6;
  int r0 = lane & 15, kb = lane >> 4;

  // ---- 1. v stage (nt loads in flight first) ----
  STAGE44_NT(v + (size_t)bh * 11264);

  // ---- 2. constants ----
  if (tid < 484) msk[tid] = mask_s[tid];
  {
    int t = tid >> 4, f = tid & 15;
    lcsw[t][f] = csw[t * 16 + f];
  }
  if (tid < 32) lcsw[tid][16] = csb[tid];

  // ---- 3. q/k direct tiles (no barrier; unique LDS scatter) ----
  const float* qbase = q + (size_t)(b * 704 + 4 * h * 22) * 256;
  const float* kbase = k + (size_t)(b * 352 + 2 * h * 22) * 256;
  for (int pass = 0; pass < 2; ++pass) {
    int u = pass == 0 ? w : 8;
    if (pass == 1 && w != 0) break;
    bool isK = u >= 6;
    int ut = isK ? u - 6 : u;
    int limit = isK ? 44 : 88;
    int rr = ut * 16 + r0;
    if (rr >= limit) rr = 0;  // clamp (results guarded on store)
    const float* src = (isK ? kbase : qbase) + (size_t)rr * 256;
    const ushort* wf = isK ? kwf : qwf;
    f32x4 acc = {0.f, 0.f, 0.f, 0.f};
    #pragma unroll
    for (int ks = 0; ks < 8; ++ks) {
      f32x4 xa = __builtin_nontemporal_load(
          reinterpret_cast<const f32x4*>(src + ks * 32 + kb * 8));
      f32x4 xb = __builtin_nontemporal_load(
          reinterpret_cast<const f32x4*>(src + ks * 32 + kb * 8 + 4));
      short8 a;
      a[0] = (short)f2bf(xa[0]); a[1] = (short)f2bf(xa[1]);
      a[2] = (short)f2bf(xa[2]); a[3] = (short)f2bf(xa[3]);
      a[4] = (short)f2bf(xb[0]); a[5] = (short)f2bf(xb[1]);
      a[6] = (short)f2bf(xb[2]); a[7] = (short)f2bf(xb[3]);
      short8 bf = *reinterpret_cast<const short8*>(wf + (ks * 64 + lane) * 8);
      acc = __builtin_amdgcn_mfma_f32_16x16x32_bf16(a, bf, acc, 0, 0, 0);
    }
    if (r0 < 8) {  // D: col = lane&15 = m, row = kb*4+reg (m89-verified)
      int m = r0;
      float bias = isK ? skb[m] : sqb[m];
      #pragma unroll
      for (int reg = 0; reg < 4; ++reg) {
        int R = ut * 16 + kb * 4 + reg;  // local row
        if (R < limit) {
          if (!isK) {
            int fo2l = R / 22, j2 = R % 22;
            int lf = fo2l * 11264 + j2 * 512 + m * 64;
            int t = lf / 1408;
            int s = (lf % 1408) >> 6;
            qs[t][s] = acc[reg] + bias;
          } else {
            int f2l = R / 22, j2 = R % 22;
            int lf = f2l * 11264 + j2 * 512 + m * 64;
            int floc = lf / 1408;
            int jj = (lf % 1408) >> 6;
            kraw[floc][jj] = acc[reg] + bias;
          }
        }
      }
    }
  }
  __syncthreads();  // lA staged + qs/kraw complete

  // ---- 4. v MFMA (R10-verified body) ----
  int nt0 = w * 4;
  f32x4 acc[3][4];
  #pragma unroll
  for (int m = 0; m < 3; ++m)
    #pragma unroll
    for (int n = 0; n < 4; ++n) acc[m][n] = (f32x4){0.f, 0.f, 0.f, 0.f};

  #pragma unroll
  for (int ks = 0; ks < 8; ++ks) {
    int go = ((ks * 4 + kb) ^ (r0 & 7)) * 8;
    short8 a0 = *reinterpret_cast<const short8*>(&lA[(r0) * 256 + go]);
    short8 a1 = *reinterpret_cast<const short8*>(&lA[(16 + r0) * 256 + go]);
    short8 a2 = *reinterpret_cast<const short8*>(&lA[(32 + r0) * 256 + go]);
    #pragma unroll
    for (int n = 0; n < 4; ++n) {
      short8 bf = *reinterpret_cast<const short8*>(
          wvtf + ((size_t)((nt0 + n) * 8 + ks) * 64 + lane) * 8);
      acc[0][n] = __builtin_amdgcn_mfma_f32_16x16x32_bf16(bf, a0, acc[0][n], 0, 0, 0);
      acc[1][n] = __builtin_amdgcn_mfma_f32_16x16x32_bf16(bf, a1, acc[1][n], 0, 0, 0);
      acc[2][n] = __builtin_amdgcn_mfma_f32_16x16x32_bf16(bf, a2, acc[2][n], 0, 0, 0);
    }
  }
  __syncthreads();  // lA reads done; sbuf becomes dump

  // ---- 5. dump/gather 4 phases -> vsg / vtl (LDS) ----
  #pragma unroll
  for (int n = 0; n < 4; ++n) {
    float4 bq = *reinterpret_cast<const float4*>(Wv_b + w * 64 + n * 16 + kb * 4);
    int dbase = tid * 13;
    #pragma unroll
    for (int m = 0; m < 3; ++m) {
      dump[dbase + m * 4 + 0] = acc[m][n][0] + bq.x;
      dump[dbase + m * 4 + 1] = acc[m][n][1] + bq.y;
      dump[dbase + m * 4 + 2] = acc[m][n][2] + bq.z;
      dump[dbase + m * 4 + 3] = acc[m][n][3] + bq.w;
    }
    __syncthreads();
    if (n < 2) {
      if (tid < 256) {
        int f = tid >> 4, rest = tid & 15;
        int kb2 = rest >> 2, reg = rest & 3;
        float s = 0.f;
        #pragma unroll
        for (int u = 0; u < 22; ++u) {
          int fj = f * 22 + u;
          int f2 = (fj >= 176) ? 1 : 0;
          int rem = fj - f2 * 176;
          int j = rem >> 3, ww = rem & 7;
          int vrow = f2 * 22 + j;
          int m = vrow >> 4, rr2 = vrow & 15;
          s += dump[(ww * 64 + kb2 * 16 + rr2) * 13 + m * 4 + reg];
        }
        vsg[f][n * 16 + kb2 * 4 + reg] = s;
      }
    } else {
      if (tid < 352) {
        int jj = tid >> 4, rest = tid & 15;
        int kb2 = rest >> 2, reg = rest & 3;
        float s = 0.f;
        #pragma unroll
        for (int f = 0; f < 16; ++f) {
          int fj = f * 22 + jj;
          int f2 = (fj >= 176) ? 1 : 0;
          int rem = fj - f2 * 176;
          int j = rem >> 3, ww = rem & 7;
          int vrow = f2 * 22 + j;
          int m = vrow >> 4, rr2 = vrow & 15;
          s += dump[(ww * 64 + kb2 * 16 + rr2) * 13 + m * 4 + reg];
        }
        vtl[jj][(n - 2) * 16 + kb2 * 4 + reg] = s;
      }
    }
    __syncthreads();
  }

  // ---- 6a. EARLY vt-half output write (t-independent): overlaps convs/softmax
  float* ob = out + (size_t)b * 32 * 22 * 512 + h * 64;
  for (int i = tid; i < 5632; i += 512) {   // 32 t x 22 s x 8 float4
    int ts = i >> 3, w4 = i & 7;
    int t = ts / 22, s = ts % 22;
    int d0 = 32 + w4 * 4;
    const float* tp = &vtl[s][d0 - 32];
    f32x4 val = {tp[0], tp[1], tp[2], tp[3]};
    *reinterpret_cast<f32x4*>(ob + (size_t)(t * 22 + s) * 512 + d0) = val;
  }

  // ---- 6b. convs: kss (704) and vss (1024) — into sbuf overlay ----
  for (int o = tid; o < 704; o += 512) {
    int t = o / 22, j = o % 22;
    float a = 32.0f * lcsw[t][16];
    #pragma unroll
    for (int f = 0; f < 16; ++f) a += lcsw[t][f] * kraw[f][j];
    kssp[t * 23 + j] = a;
  }
  {
    int t = tid >> 4, d2 = (tid & 15) * 2;
    float a0 = 22.0f * lcsw[t][16], a1 = a0;
    #pragma unroll
    for (int f = 0; f < 16; ++f) {
      float cw = lcsw[t][f];
      a0 += cw * vsg[f][d2];
      a1 += cw * vsg[f][d2 + 1];
    }
    vssp[t * 33 + d2] = a0;
    vssp[t * 33 + d2 + 1] = a1;
  }
  __syncthreads();

  // ---- 7. diag softmax (704) ----
  for (int p = tid; p < 704; p += 512) {
    int t = p / 22, s = p % 22;
    float qv = qs[t][s];
    float mx = -3.0e38f;
    #pragma unroll
    for (int u = 0; u < 22; ++u) {
      float av = msk[s * 22 + u] ? qv * kssp[t * 23 + u] : NEGV;
      mx = fmaxf(mx, av);
    }
    float den = 0.f;
    #pragma unroll
    for (int u = 0; u < 22; ++u) {
      float av = msk[s * 22 + u] ? qv * kssp[t * 23 + u] : NEGV;
      den += expf(av - mx);
    }
    float as = msk[s * 22 + s] ? qv * kssp[t * 23 + s] : NEGV;
    dgp[t * 23 + s] = expf(as - mx) / den;
  }
  __syncthreads();

  // ---- 8. vs-half output write (plain stores) ----
  for (int i = tid; i < 5632; i += 512) {   // 32 t x 22 s x 8 float4
    int ts = i >> 3, w4 = i & 7;
    int t = ts / 22, s = ts % 22;
    int d0 = w4 * 4;
    float g = dgp[t * 23 + s];
    const float* vp = &vssp[t * 33 + d0];
    f32x4 val = {g * vp[0], g * vp[1], g * vp[2], g * vp[3]};
    *reinterpret_cast<f32x4*>(ob + (size_t)(t * 22 + s) * 512 + d0) = val;
  }
}

extern "C" void kernel_launch(void* const* d_in, const int* in_sizes, int n_in,
                              void* d_out, int out_size, void* d_ws, size_t ws_size,
                              hipStream_t stream) {
  const float* q = (const float*)d_in[0];
  const float* k = (const float*)d_in[1];
  const float* v = (const float*)d_in[2];
  const int* mask_s = (const int*)d_in[3];
  const float* Wq_w = (const float*)d_in[5];
  const float* Wq_b = (const float*)d_in[6];
  const float* Wk_w = (const float*)d_in[7];
  const float* Wk_b = (const float*)d_in[8];
  const float* Wv_w = (const float*)d_in[9];
  const float* Wv_b = (const float*)d_in[10];
  const float* csw = (const float*)d_in[11];
  const float* csb = (const float*)d_in[12];
  float* out = (float*)d_out;

  float* ws = (float*)d_ws;
  float* sqb = ws;                            // 8
  float* skb = ws + 8;                        // 8 -> 16
  ushort* wvtf = (ushort*)(ws + 16);          // 131072 us -> ends f-idx 65552
  ushort* qwf = (ushort*)(ws + 65552);        // 4096 us -> 67600
  ushort* kwf = (ushort*)(ws + 67600);        // 4096 us -> 69648

  hipLaunchKernelGGL(prep_all_kernel, dim3(273), dim3(512), 0, stream,
                     Wq_w, Wq_b, Wk_w, Wk_b, Wv_w, qwf, kwf, wvtf, sqb, skb);
  hipLaunchKernelGGL(mega_kernel, dim3(2048), dim3(512), 0, stream,
                     q, k, v, qwf, kwf, wvtf, sqb, skb, Wv_b, csw, csb, mask_s, out);
}